// Round 1
// baseline (1032.874 us; speedup 1.0000x reference)
//
#include <hip/hip_runtime.h>
#include <math.h>

#define H 1024
#define H3 3072
#define NVOC 256

__device__ __forceinline__ float sigf(float x) { return 1.0f / (1.0f + expf(-x)); }

// C[M,N] = A[M,K] @ W[N,K]^T + bias, optional ReLU. All row-major, K-contiguous.
template<int BM, int BN, int BK, int TM, int TN, bool RELU>
__global__ __launch_bounds__((BM / TM) * (BN / TN))
void gemm_bt(const float* __restrict__ A, const float* __restrict__ W,
             const float* __restrict__ bias, float* __restrict__ C,
             int M, int N, int K)
{
    constexpr int TX = BN / TN, TY = BM / TM, NT = TX * TY;
    __shared__ float As[BK][BM + 4];
    __shared__ float Ws[BK][BN + 4];
    const int tid = threadIdx.x;
    const int tx = tid % TX, ty = tid / TX;
    const int bm = blockIdx.y * BM, bn = blockIdx.x * BN;

    float acc[TM][TN];
#pragma unroll
    for (int i = 0; i < TM; i++)
#pragma unroll
        for (int j = 0; j < TN; j++) acc[i][j] = 0.f;

    const float* Ab = A + (size_t)bm * K;
    const float* Wb = W + (size_t)bn * K;

    for (int k0 = 0; k0 < K; k0 += BK) {
        constexpr int PA = (BM * BK) / (NT * 4);
#pragma unroll
        for (int p = 0; p < PA; p++) {
            int lin = (p * NT + tid) * 4;
            int r = lin / BK, c = lin % BK;
            float4 v = *reinterpret_cast<const float4*>(Ab + (size_t)r * K + k0 + c);
            As[c + 0][r] = v.x; As[c + 1][r] = v.y; As[c + 2][r] = v.z; As[c + 3][r] = v.w;
        }
        constexpr int PW = (BN * BK) / (NT * 4);
#pragma unroll
        for (int p = 0; p < PW; p++) {
            int lin = (p * NT + tid) * 4;
            int r = lin / BK, c = lin % BK;
            float4 v = *reinterpret_cast<const float4*>(Wb + (size_t)r * K + k0 + c);
            Ws[c + 0][r] = v.x; Ws[c + 1][r] = v.y; Ws[c + 2][r] = v.z; Ws[c + 3][r] = v.w;
        }
        __syncthreads();
#pragma unroll
        for (int k = 0; k < BK; k++) {
            float a[TM], b[TN];
#pragma unroll
            for (int i = 0; i < TM; i += 4) {
                float4 t = *reinterpret_cast<const float4*>(&As[k][ty * TM + i]);
                a[i] = t.x; a[i + 1] = t.y; a[i + 2] = t.z; a[i + 3] = t.w;
            }
#pragma unroll
            for (int j = 0; j < TN; j += 4) {
                float4 t = *reinterpret_cast<const float4*>(&Ws[k][tx * TN + j]);
                b[j] = t.x; b[j + 1] = t.y; b[j + 2] = t.z; b[j + 3] = t.w;
            }
#pragma unroll
            for (int i = 0; i < TM; i++)
#pragma unroll
                for (int j = 0; j < TN; j++)
                    acc[i][j] = fmaf(a[i], b[j], acc[i][j]);
        }
        __syncthreads();
    }
#pragma unroll
    for (int i = 0; i < TM; i++) {
        int row = bm + ty * TM + i;
#pragma unroll
        for (int j = 0; j < TN; j += 4) {
            int col = bn + tx * TN + j;
            float4 v;
            v.x = acc[i][j + 0] + bias[col + 0];
            v.y = acc[i][j + 1] + bias[col + 1];
            v.z = acc[i][j + 2] + bias[col + 2];
            v.w = acc[i][j + 3] + bias[col + 3];
            if (RELU) {
                v.x = fmaxf(v.x, 0.f); v.y = fmaxf(v.y, 0.f);
                v.z = fmaxf(v.z, 0.f); v.w = fmaxf(v.w, 0.f);
            }
            *reinterpret_cast<float4*>(C + (size_t)row * N + col) = v;
        }
    }
}

// out[n] = dot(x, Wm[n,:]) + bias[n]; one wave per output row.
__global__ void gemv_bt(const float* __restrict__ x, const float* __restrict__ Wm,
                        const float* __restrict__ bias, float* __restrict__ out,
                        int N, int K)
{
    int wid = threadIdx.x >> 6;
    int lane = threadIdx.x & 63;
    int n = blockIdx.x * (blockDim.x >> 6) + wid;
    if (n >= N) return;
    const float* wr = Wm + (size_t)n * K;
    float s = 0.f;
    for (int p = 0; p < K; p += 256) {
        float4 xv = *reinterpret_cast<const float4*>(x + p + lane * 4);
        float4 wv = *reinterpret_cast<const float4*>(wr + p + lane * 4);
        s = fmaf(xv.x, wv.x, s); s = fmaf(xv.y, wv.y, s);
        s = fmaf(xv.z, wv.z, s); s = fmaf(xv.w, wv.w, s);
    }
#pragma unroll
    for (int off = 32; off; off >>= 1) s += __shfl_down(s, off);
    if (lane == 0) out[n] = s + (bias ? bias[n] : 0.f);
}

// h1[v,h] = GRU(Gi[v], gh0, state) for the 256 distinct first-step states
__global__ void h1_combine(const float* __restrict__ Gi, const float* __restrict__ gh0,
                           const float* __restrict__ state, float* __restrict__ h1)
{
    int idx = blockIdx.x * blockDim.x + threadIdx.x;
    int v = idx >> 10, h = idx & (H - 1);
    const float* g = Gi + (size_t)v * H3;
    float r = sigf(g[h] + gh0[h]);
    float z = sigf(g[H + h] + gh0[H + h]);
    float n = tanhf(fmaf(r, gh0[2 * H + h], g[2 * H + h]));
    h1[idx] = (1.f - z) * n + z * state[h];
}

// step 2: out[row] = GRU(Gi[t1], gh1[t0], h1[t0])  (used for rel->h2 and attr->clause)
__global__ void step2_combine(const int* __restrict__ toks, int tstride,
                              const float* __restrict__ Gi, const float* __restrict__ gh1,
                              const float* __restrict__ h1, float* __restrict__ out)
{
    int idx = blockIdx.x * blockDim.x + threadIdx.x;
    int row = idx >> 10, h = idx & (H - 1);
    int t0 = toks[row * tstride + 0];
    int t1 = toks[row * tstride + 1];
    const float* g = Gi + (size_t)t1 * H3;
    const float* gh = gh1 + (size_t)t0 * H3;
    float r = sigf(g[h] + gh[h]);
    float z = sigf(g[H + h] + gh[H + h]);
    float n = tanhf(fmaf(r, gh[2 * H + h], g[2 * H + h]));
    out[idx] = (1.f - z) * n + z * h1[(size_t)t0 * H + h];
}

// step 3 (rel only): out[row] = GRU(Gi[t2], gh2[row], h2[row])
__global__ void step3_combine(const int* __restrict__ toks,
                              const float* __restrict__ Gi, const float* __restrict__ gh2,
                              const float* __restrict__ h2, float* __restrict__ out)
{
    int idx = blockIdx.x * blockDim.x + threadIdx.x;
    int row = idx >> 10, h = idx & (H - 1);
    int t2 = toks[row * 3 + 2];
    const float* g = Gi + (size_t)t2 * H3;
    const float* gh = gh2 + (size_t)row * H3;
    float r = sigf(g[h] + gh[h]);
    float z = sigf(g[H + h] + gh[H + h]);
    float n = tanhf(fmaf(r, gh[2 * H + h], g[2 * H + h]));
    out[idx] = (1.f - z) * n + z * h2[idx];
}

// single-block softmax over N logits + eps smoothing (b3 is softmax-invariant)
__global__ void softmax_eps(const float* __restrict__ logits, const float* __restrict__ epsp,
                            float* __restrict__ out, int N)
{
    __shared__ float smax[16], ssum[16];
    int tid = threadIdx.x;
    int nw = blockDim.x >> 6;
    float m = -INFINITY;
    for (int i = tid; i < N; i += blockDim.x) m = fmaxf(m, logits[i]);
#pragma unroll
    for (int off = 32; off; off >>= 1) m = fmaxf(m, __shfl_down(m, off));
    if ((tid & 63) == 0) smax[tid >> 6] = m;
    __syncthreads();
    float M = smax[0];
    for (int i = 1; i < nw; i++) M = fmaxf(M, smax[i]);
    float s = 0.f;
    for (int i = tid; i < N; i += blockDim.x) s += expf(logits[i] - M);
#pragma unroll
    for (int off = 32; off; off >>= 1) s += __shfl_down(s, off);
    if ((tid & 63) == 0) ssum[tid >> 6] = s;
    __syncthreads();
    float S = 0.f;
    for (int i = 0; i < nw; i++) S += ssum[i];
    float e = epsp[0];
    float mul = (1.f - e) / S;
    float add = e / (float)N;
    for (int i = tid; i < N; i += blockDim.x) out[i] = expf(logits[i] - M) * mul + add;
}

extern "C" void kernel_launch(void* const* d_in, const int* in_sizes, int n_in,
                              void* d_out, int out_size, void* d_ws, size_t ws_size,
                              hipStream_t stream)
{
    const float* state       = (const float*)d_in[0];
    const int*   rel_tokens  = (const int*)d_in[1];
    const int*   attr_tokens = (const int*)d_in[2];
    const float* table       = (const float*)d_in[3];
    const float* W_emb       = (const float*)d_in[4];
    const float* b_emb       = (const float*)d_in[5];
    const float* W_ih        = (const float*)d_in[6];
    const float* W_hh        = (const float*)d_in[7];
    const float* b_ih        = (const float*)d_in[8];
    const float* b_hh        = (const float*)d_in[9];
    const float* W1          = (const float*)d_in[10];
    const float* b1          = (const float*)d_in[11];
    const float* W2          = (const float*)d_in[12];
    const float* b2          = (const float*)d_in[13];
    const float* W3          = (const float*)d_in[14];
    // d_in[15] = b3: constant shift on logits -> softmax-invariant, skipped.
    const float* eps         = (const float*)d_in[16];

    const int Nr = in_sizes[1] / 3;   // 4096
    const int Na = in_sizes[2] / 2;   // 4096
    const int Ntot = Nr + Na;         // 8192

    float* ws     = (float*)d_ws;
    float* emb    = ws;                               // 256*1024
    float* Gi     = emb + NVOC * H;                   // 256*3072
    float* gh0    = Gi + NVOC * H3;                   // 3072
    float* h1     = gh0 + H3;                         // 256*1024
    float* gh1    = h1 + NVOC * H;                    // 256*3072
    float* h2     = gh1 + NVOC * H3;                  // Nr*1024
    float* gh2    = h2 + (size_t)Nr * H;              // Nr*3072
    float* clause = gh2 + (size_t)Nr * H3;            // Ntot*1024
    float* x1     = gh2;                              // alias: gh2 dead after step3
    float* x2     = clause + (size_t)Ntot * H;        // Ntot*1024
    float* logits = x2 + (size_t)Ntot * H;            // Ntot

    // K1: emb = table @ W_emb^T + b_emb                [256,1024]
    gemm_bt<64, 64, 32, 4, 4, false><<<dim3(H / 64, NVOC / 64), 256, 0, stream>>>(
        table, W_emb, b_emb, emb, NVOC, H, H);
    // K2: Gi = emb @ W_ih^T + b_ih                     [256,3072]
    gemm_bt<64, 64, 32, 4, 4, false><<<dim3(H3 / 64, NVOC / 64), 256, 0, stream>>>(
        emb, W_ih, b_ih, Gi, NVOC, H3, H);
    // K3: gh0 = state @ W_hh^T + b_hh                  [3072]
    gemv_bt<<<H3 / 4, 256, 0, stream>>>(state, W_hh, b_hh, gh0, H3, H);
    // K4: h1[v] for the 256 distinct tokens
    h1_combine<<<NVOC * H / 256, 256, 0, stream>>>(Gi, gh0, state, h1);
    // K5: gh1 = h1 @ W_hh^T + b_hh                     [256,3072]
    gemm_bt<64, 64, 32, 4, 4, false><<<dim3(H3 / 64, NVOC / 64), 256, 0, stream>>>(
        h1, W_hh, b_hh, gh1, NVOC, H3, H);
    // K6a: rel step 2 -> h2 (per-row gather + combine, no GEMM)
    step2_combine<<<Nr * (H / 256), 256, 0, stream>>>(rel_tokens, 3, Gi, gh1, h1, h2);
    // K6b: attr step 2 -> clause rows [Nr, Nr+Na)  (whole attr branch, no GEMM)
    step2_combine<<<Na * (H / 256), 256, 0, stream>>>(attr_tokens, 2, Gi, gh1, h1,
                                                      clause + (size_t)Nr * H);
    // K7: gh2 = h2 @ W_hh^T + b_hh                     [4096,3072]  (the big GEMM)
    gemm_bt<128, 128, 32, 8, 8, false><<<dim3(H3 / 128, Nr / 128), 256, 0, stream>>>(
        h2, W_hh, b_hh, gh2, Nr, H3, H);
    // K8: rel step 3 -> clause rows [0, Nr)
    step3_combine<<<Nr * (H / 256), 256, 0, stream>>>(rel_tokens, Gi, gh2, h2, clause);
    // K9: x1 = relu(clause @ W1^T + b1)                [8192,1024]
    gemm_bt<128, 128, 32, 8, 8, true><<<dim3(H / 128, Ntot / 128), 256, 0, stream>>>(
        clause, W1, b1, x1, Ntot, H, H);
    // K10: x2 = relu(x1 @ W2^T + b2)                   [8192,1024]
    gemm_bt<128, 128, 32, 8, 8, true><<<dim3(H / 128, Ntot / 128), 256, 0, stream>>>(
        x1, W2, b2, x2, Ntot, H, H);
    // K11: logits[n] = dot(x2[n], W3)                  [8192]
    gemv_bt<<<Ntot / 4, 256, 0, stream>>>(W3, x2, nullptr, logits, Ntot, H);
    // K12: softmax + eps smoothing -> d_out
    softmax_eps<<<1, 1024, 0, stream>>>(logits, eps, (float*)d_out, Ntot);
}

// Round 2
// 424.219 us; speedup vs baseline: 2.4348x; 2.4348x over previous
//
#include <hip/hip_runtime.h>
#include <math.h>

#define H 1024
#define H3 3072
#define NVOC 256

typedef __attribute__((ext_vector_type(8))) short bf16x8;
typedef __attribute__((ext_vector_type(4))) float f32x4;

__device__ __forceinline__ float sigf(float x) { return 1.0f / (1.0f + expf(-x)); }

__device__ __forceinline__ unsigned short f2bf(float f) {
    unsigned int u = __float_as_uint(f);
    u = (u + 0x7fffu + ((u >> 16) & 1u)) >> 16;   // RNE
    return (unsigned short)u;
}

// ---------------- fp32 tiled GEMM (small matrices only) ----------------
template<int BM, int BN, int BK, int TM, int TN, bool RELU>
__global__ __launch_bounds__((BM / TM) * (BN / TN))
void gemm_bt(const float* __restrict__ A, const float* __restrict__ W,
             const float* __restrict__ bias, float* __restrict__ C,
             int M, int N, int K)
{
    constexpr int TX = BN / TN, TY = BM / TM, NT = TX * TY;
    __shared__ float As[BK][BM + 4];
    __shared__ float Ws[BK][BN + 4];
    const int tid = threadIdx.x;
    const int tx = tid % TX, ty = tid / TX;
    const int bm = blockIdx.y * BM, bn = blockIdx.x * BN;

    float acc[TM][TN];
#pragma unroll
    for (int i = 0; i < TM; i++)
#pragma unroll
        for (int j = 0; j < TN; j++) acc[i][j] = 0.f;

    const float* Ab = A + (size_t)bm * K;
    const float* Wb = W + (size_t)bn * K;

    for (int k0 = 0; k0 < K; k0 += BK) {
        constexpr int PA = (BM * BK) / (NT * 4);
#pragma unroll
        for (int p = 0; p < PA; p++) {
            int lin = (p * NT + tid) * 4;
            int r = lin / BK, c = lin % BK;
            float4 v = *reinterpret_cast<const float4*>(Ab + (size_t)r * K + k0 + c);
            As[c + 0][r] = v.x; As[c + 1][r] = v.y; As[c + 2][r] = v.z; As[c + 3][r] = v.w;
        }
        constexpr int PW = (BN * BK) / (NT * 4);
#pragma unroll
        for (int p = 0; p < PW; p++) {
            int lin = (p * NT + tid) * 4;
            int r = lin / BK, c = lin % BK;
            float4 v = *reinterpret_cast<const float4*>(Wb + (size_t)r * K + k0 + c);
            Ws[c + 0][r] = v.x; Ws[c + 1][r] = v.y; Ws[c + 2][r] = v.z; Ws[c + 3][r] = v.w;
        }
        __syncthreads();
#pragma unroll
        for (int k = 0; k < BK; k++) {
            float a[TM], b[TN];
#pragma unroll
            for (int i = 0; i < TM; i += 4) {
                float4 t = *reinterpret_cast<const float4*>(&As[k][ty * TM + i]);
                a[i] = t.x; a[i + 1] = t.y; a[i + 2] = t.z; a[i + 3] = t.w;
            }
#pragma unroll
            for (int j = 0; j < TN; j += 4) {
                float4 t = *reinterpret_cast<const float4*>(&Ws[k][tx * TN + j]);
                b[j] = t.x; b[j + 1] = t.y; b[j + 2] = t.z; b[j + 3] = t.w;
            }
#pragma unroll
            for (int i = 0; i < TM; i++)
#pragma unroll
                for (int j = 0; j < TN; j++)
                    acc[i][j] = fmaf(a[i], b[j], acc[i][j]);
        }
        __syncthreads();
    }
#pragma unroll
    for (int i = 0; i < TM; i++) {
        int row = bm + ty * TM + i;
#pragma unroll
        for (int j = 0; j < TN; j += 4) {
            int col = bn + tx * TN + j;
            float4 v;
            v.x = acc[i][j + 0] + bias[col + 0];
            v.y = acc[i][j + 1] + bias[col + 1];
            v.z = acc[i][j + 2] + bias[col + 2];
            v.w = acc[i][j + 3] + bias[col + 3];
            if (RELU) {
                v.x = fmaxf(v.x, 0.f); v.y = fmaxf(v.y, 0.f);
                v.z = fmaxf(v.z, 0.f); v.w = fmaxf(v.w, 0.f);
            }
            *reinterpret_cast<float4*>(C + (size_t)row * N + col) = v;
        }
    }
}

// ---------------- bf16 MFMA GEMM (m97 structure: 128x128 tile, BK=32) ----------
// C[M,N] = A[M,K] @ W[N,K]^T + bias. A,W bf16 (K-contiguous); C fp32 or bf16.
template<bool RELU, bool OUT_BF16>
__global__ __launch_bounds__(256)
void gemm_bf16(const unsigned short* __restrict__ A, const unsigned short* __restrict__ W,
               const float* __restrict__ bias, void* __restrict__ C,
               int N, int K, int gx)
{
    __shared__ unsigned short As[128 * 32];
    __shared__ unsigned short Ws[128 * 32];
    const int tid = threadIdx.x;
    const int wid = tid >> 6, lane = tid & 63;

    // XCD-aware bijective swizzle (grid % 8 == 0 for all our launches)
    const int nwg = gridDim.x;
    const int cpx = nwg >> 3;
    const int bid = blockIdx.x;
    const int swz = (bid & 7) * cpx + (bid >> 3);
    const int bm = (swz / gx) * 128;
    const int bn = (swz % gx) * 128;

    const int wm = (wid >> 1) * 64, wn = (wid & 1) * 64;

    f32x4 acc[4][4];
#pragma unroll
    for (int i = 0; i < 4; i++)
#pragma unroll
        for (int j = 0; j < 4; j++) acc[i][j] = (f32x4){0.f, 0.f, 0.f, 0.f};

    const int l4 = lane >> 2;          // 0..15: row within 16-row chunk
    const int c8 = (lane & 3) * 8;     // 0,8,16,24: col start
    const int fr = lane & 15;          // fragment row/col
    const int fq = lane >> 4;          // 0..3: k-group / out row group

    for (int k0 = 0; k0 < K; k0 += 32) {
#pragma unroll
        for (int issue = 0; issue < 2; issue++) {
            const int chunk = issue * 4 + wid;          // 0..7
            const int row = chunk * 16 + l4;            // 0..127
            const unsigned short* ga = A + (size_t)(bm + row) * K + k0 + c8;
            const unsigned short* gw = W + (size_t)(bn + row) * K + k0 + c8;
            __builtin_amdgcn_global_load_lds(
                (const __attribute__((address_space(1))) void*)ga,
                (__attribute__((address_space(3))) void*)(As + chunk * 512), 16, 0, 0);
            __builtin_amdgcn_global_load_lds(
                (const __attribute__((address_space(1))) void*)gw,
                (__attribute__((address_space(3))) void*)(Ws + chunk * 512), 16, 0, 0);
        }
        __syncthreads();

        bf16x8 a[4], b[4];
#pragma unroll
        for (int m = 0; m < 4; m++)
            a[m] = *reinterpret_cast<const bf16x8*>(As + (wm + m * 16 + fr) * 32 + fq * 8);
#pragma unroll
        for (int n = 0; n < 4; n++)
            b[n] = *reinterpret_cast<const bf16x8*>(Ws + (wn + n * 16 + fr) * 32 + fq * 8);
#pragma unroll
        for (int m = 0; m < 4; m++)
#pragma unroll
            for (int n = 0; n < 4; n++)
                acc[m][n] = __builtin_amdgcn_mfma_f32_16x16x32_bf16(a[m], b[n], acc[m][n], 0, 0, 0);
        __syncthreads();
    }

#pragma unroll
    for (int m = 0; m < 4; m++) {
#pragma unroll
        for (int n = 0; n < 4; n++) {
            const int col = bn + wn + n * 16 + fr;
            const float bv = bias[col];
#pragma unroll
            for (int j = 0; j < 4; j++) {
                const int row = bm + wm + m * 16 + fq * 4 + j;
                float v = acc[m][n][j] + bv;
                if (RELU) v = fmaxf(v, 0.f);
                if (OUT_BF16)
                    ((unsigned short*)C)[(size_t)row * N + col] = f2bf(v);
                else
                    ((float*)C)[(size_t)row * N + col] = v;
            }
        }
    }
}

// ---------------- fp32 -> bf16 conversion (weights) ----------------
__global__ void cvt_bf16(const float* __restrict__ in, unsigned short* __restrict__ out, int n)
{
    int i = (blockIdx.x * blockDim.x + threadIdx.x) * 4;
    if (i >= n) return;
    float4 v = *reinterpret_cast<const float4*>(in + i);
    ushort4 o;
    o.x = f2bf(v.x); o.y = f2bf(v.y); o.z = f2bf(v.z); o.w = f2bf(v.w);
    *reinterpret_cast<ushort4*>(out + i) = o;
}

// ---------------- GEMV: out[n] = dot(x, Wm[n,:]) + bias ----------------
__global__ void gemv_bt(const float* __restrict__ x, const float* __restrict__ Wm,
                        const float* __restrict__ bias, float* __restrict__ out,
                        int N, int K)
{
    int wid = threadIdx.x >> 6;
    int lane = threadIdx.x & 63;
    int n = blockIdx.x * (blockDim.x >> 6) + wid;
    if (n >= N) return;
    const float* wr = Wm + (size_t)n * K;
    float s = 0.f;
    for (int p = 0; p < K; p += 256) {
        float4 xv = *reinterpret_cast<const float4*>(x + p + lane * 4);
        float4 wv = *reinterpret_cast<const float4*>(wr + p + lane * 4);
        s = fmaf(xv.x, wv.x, s); s = fmaf(xv.y, wv.y, s);
        s = fmaf(xv.z, wv.z, s); s = fmaf(xv.w, wv.w, s);
    }
#pragma unroll
    for (int off = 32; off; off >>= 1) s += __shfl_down(s, off);
    if (lane == 0) out[n] = s + (bias ? bias[n] : 0.f);
}

// ---------------- GRU combine kernels ----------------
__global__ void h1_combine(const float* __restrict__ Gi, const float* __restrict__ gh0,
                           const float* __restrict__ state, float* __restrict__ h1)
{
    int idx = blockIdx.x * blockDim.x + threadIdx.x;
    int v = idx >> 10, h = idx & (H - 1);
    const float* g = Gi + (size_t)v * H3;
    float r = sigf(g[h] + gh0[h]);
    float z = sigf(g[H + h] + gh0[H + h]);
    float n = tanhf(fmaf(r, gh0[2 * H + h], g[2 * H + h]));
    h1[idx] = (1.f - z) * n + z * state[h];
}

// rel step 2: write fp32 h2 (for step3) + bf16 h2b (for K7 GEMM)
__global__ void step2_rel(const int* __restrict__ toks,
                          const float* __restrict__ Gi, const float* __restrict__ gh1,
                          const float* __restrict__ h1,
                          float* __restrict__ out, unsigned short* __restrict__ outb)
{
    int idx = blockIdx.x * blockDim.x + threadIdx.x;
    int row = idx >> 10, h = idx & (H - 1);
    int t0 = toks[row * 3 + 0];
    int t1 = toks[row * 3 + 1];
    const float* g = Gi + (size_t)t1 * H3;
    const float* gh = gh1 + (size_t)t0 * H3;
    float r = sigf(g[h] + gh[h]);
    float z = sigf(g[H + h] + gh[H + h]);
    float n = tanhf(fmaf(r, gh[2 * H + h], g[2 * H + h]));
    float v = (1.f - z) * n + z * h1[(size_t)t0 * H + h];
    out[idx] = v;
    outb[idx] = f2bf(v);
}

// attr step 2 (final attr state): bf16 only (feeds K9 GEMM)
__global__ void step2_attr(const int* __restrict__ toks,
                           const float* __restrict__ Gi, const float* __restrict__ gh1,
                           const float* __restrict__ h1, unsigned short* __restrict__ outb)
{
    int idx = blockIdx.x * blockDim.x + threadIdx.x;
    int row = idx >> 10, h = idx & (H - 1);
    int t0 = toks[row * 2 + 0];
    int t1 = toks[row * 2 + 1];
    const float* g = Gi + (size_t)t1 * H3;
    const float* gh = gh1 + (size_t)t0 * H3;
    float r = sigf(g[h] + gh[h]);
    float z = sigf(g[H + h] + gh[H + h]);
    float n = tanhf(fmaf(r, gh[2 * H + h], g[2 * H + h]));
    outb[idx] = f2bf((1.f - z) * n + z * h1[(size_t)t0 * H + h]);
}

// rel step 3: bf16 clause rows [0, Nr)
__global__ void step3_rel(const int* __restrict__ toks,
                          const float* __restrict__ Gi, const float* __restrict__ gh2,
                          const float* __restrict__ h2, unsigned short* __restrict__ outb)
{
    int idx = blockIdx.x * blockDim.x + threadIdx.x;
    int row = idx >> 10, h = idx & (H - 1);
    int t2 = toks[row * 3 + 2];
    const float* g = Gi + (size_t)t2 * H3;
    const float* gh = gh2 + (size_t)row * H3;
    float r = sigf(g[h] + gh[h]);
    float z = sigf(g[H + h] + gh[H + h]);
    float n = tanhf(fmaf(r, gh[2 * H + h], g[2 * H + h]));
    outb[idx] = f2bf((1.f - z) * n + z * h2[idx]);
}

// ---------------- softmax + eps smoothing ----------------
__global__ void softmax_eps(const float* __restrict__ logits, const float* __restrict__ epsp,
                            float* __restrict__ out, int N)
{
    __shared__ float smax[16], ssum[16];
    int tid = threadIdx.x;
    int nw = blockDim.x >> 6;
    float m = -INFINITY;
    for (int i = tid; i < N; i += blockDim.x) m = fmaxf(m, logits[i]);
#pragma unroll
    for (int off = 32; off; off >>= 1) m = fmaxf(m, __shfl_down(m, off));
    if ((tid & 63) == 0) smax[tid >> 6] = m;
    __syncthreads();
    float M = smax[0];
    for (int i = 1; i < nw; i++) M = fmaxf(M, smax[i]);
    float s = 0.f;
    for (int i = tid; i < N; i += blockDim.x) s += expf(logits[i] - M);
#pragma unroll
    for (int off = 32; off; off >>= 1) s += __shfl_down(s, off);
    if ((tid & 63) == 0) ssum[tid >> 6] = s;
    __syncthreads();
    float S = 0.f;
    for (int i = 0; i < nw; i++) S += ssum[i];
    float e = epsp[0];
    float mul = (1.f - e) / S;
    float add = e / (float)N;
    for (int i = tid; i < N; i += blockDim.x) out[i] = expf(logits[i] - M) * mul + add;
}

extern "C" void kernel_launch(void* const* d_in, const int* in_sizes, int n_in,
                              void* d_out, int out_size, void* d_ws, size_t ws_size,
                              hipStream_t stream)
{
    const float* state       = (const float*)d_in[0];
    const int*   rel_tokens  = (const int*)d_in[1];
    const int*   attr_tokens = (const int*)d_in[2];
    const float* table       = (const float*)d_in[3];
    const float* W_emb       = (const float*)d_in[4];
    const float* b_emb       = (const float*)d_in[5];
    const float* W_ih        = (const float*)d_in[6];
    const float* W_hh        = (const float*)d_in[7];
    const float* b_ih        = (const float*)d_in[8];
    const float* b_hh        = (const float*)d_in[9];
    const float* W1          = (const float*)d_in[10];
    const float* b1          = (const float*)d_in[11];
    const float* W2          = (const float*)d_in[12];
    const float* b2          = (const float*)d_in[13];
    const float* W3          = (const float*)d_in[14];
    // d_in[15] = b3: softmax-invariant, skipped.
    const float* eps         = (const float*)d_in[16];

    const int Nr = in_sizes[1] / 3;   // 4096
    const int Na = in_sizes[2] / 2;   // 4096
    const int Ntot = Nr + Na;         // 8192

    float* ws     = (float*)d_ws;
    float* emb    = ws;                               // 256*1024
    float* Gi     = emb + NVOC * H;                   // 256*3072
    float* gh0    = Gi + NVOC * H3;                   // 3072
    float* h1     = gh0 + H3;                         // 256*1024
    float* gh1    = h1 + NVOC * H;                    // 256*3072
    float* h2     = gh1 + NVOC * H3;                  // Nr*1024
    float* gh2    = h2 + (size_t)Nr * H;              // Nr*3072  (48 MB)
    float* x2     = gh2;                              // alias: gh2 dead after step3
    float* logits = gh2 + (size_t)Nr * H3;            // Ntot
    unsigned short* W_hhb   = (unsigned short*)(logits + Ntot);
    unsigned short* W1b     = W_hhb + (size_t)H3 * H;
    unsigned short* W2b     = W1b + (size_t)H * H;
    unsigned short* h2b     = W2b + (size_t)H * H;          // Nr*1024
    unsigned short* clauseb = h2b + (size_t)Nr * H;         // Ntot*1024
    unsigned short* x1b     = clauseb + (size_t)Ntot * H;   // Ntot*1024

    // W0: weight conversions (independent of everything else)
    cvt_bf16<<<(H3 * H / 4 + 255) / 256, 256, 0, stream>>>(W_hh, W_hhb, H3 * H);
    cvt_bf16<<<(H * H / 4 + 255) / 256, 256, 0, stream>>>(W1, W1b, H * H);
    cvt_bf16<<<(H * H / 4 + 255) / 256, 256, 0, stream>>>(W2, W2b, H * H);

    // K1: emb = table @ W_emb^T + b_emb                [256,1024]  fp32
    gemm_bt<64, 64, 32, 4, 4, false><<<dim3(H / 64, NVOC / 64), 256, 0, stream>>>(
        table, W_emb, b_emb, emb, NVOC, H, H);
    // K2: Gi = emb @ W_ih^T + b_ih                     [256,3072]  fp32
    gemm_bt<64, 64, 32, 4, 4, false><<<dim3(H3 / 64, NVOC / 64), 256, 0, stream>>>(
        emb, W_ih, b_ih, Gi, NVOC, H3, H);
    // K3: gh0 = state @ W_hh^T + b_hh                  [3072]
    gemv_bt<<<H3 / 4, 256, 0, stream>>>(state, W_hh, b_hh, gh0, H3, H);
    // K4: h1[v] for the 256 distinct tokens
    h1_combine<<<NVOC * H / 256, 256, 0, stream>>>(Gi, gh0, state, h1);
    // K5: gh1 = h1 @ W_hh^T + b_hh                     [256,3072]  fp32
    gemm_bt<64, 64, 32, 4, 4, false><<<dim3(H3 / 64, NVOC / 64), 256, 0, stream>>>(
        h1, W_hh, b_hh, gh1, NVOC, H3, H);
    // K6a: rel step 2 -> h2 (fp32) + h2b (bf16)
    step2_rel<<<Nr * (H / 256), 256, 0, stream>>>(rel_tokens, Gi, gh1, h1, h2, h2b);
    // K6b: attr step 2 -> clauseb rows [Nr, Nr+Na)
    step2_attr<<<Na * (H / 256), 256, 0, stream>>>(attr_tokens, Gi, gh1, h1,
                                                   clauseb + (size_t)Nr * H);
    // K7: gh2 = h2 @ W_hh^T + b_hh                     [4096,3072]  bf16 MFMA
    gemm_bf16<false, false><<<(H3 / 128) * (Nr / 128), 256, 0, stream>>>(
        h2b, W_hhb, b_hh, gh2, H3, H, H3 / 128);
    // K8: rel step 3 -> clauseb rows [0, Nr)
    step3_rel<<<Nr * (H / 256), 256, 0, stream>>>(rel_tokens, Gi, gh2, h2, clauseb);
    // K9: x1b = relu(clause @ W1^T + b1)               [8192,1024]  bf16 MFMA
    gemm_bf16<true, true><<<(H / 128) * (Ntot / 128), 256, 0, stream>>>(
        clauseb, W1b, b1, x1b, H, H, H / 128);
    // K10: x2 = relu(x1 @ W2^T + b2)                   [8192,1024]  bf16 MFMA
    gemm_bf16<true, false><<<(H / 128) * (Ntot / 128), 256, 0, stream>>>(
        x1b, W2b, b2, x2, H, H, H / 128);
    // K11: logits[n] = dot(x2[n], W3)                  [8192]
    gemv_bt<<<Ntot / 4, 256, 0, stream>>>(W3, x2, nullptr, logits, Ntot, H);
    // K12: softmax + eps smoothing -> d_out
    softmax_eps<<<1, 1024, 0, stream>>>(logits, eps, (float*)d_out, Ntot);
}

// Round 3
// 352.964 us; speedup vs baseline: 2.9263x; 1.2019x over previous
//
#include <hip/hip_runtime.h>
#include <math.h>

#define H 1024
#define H3 3072
#define NVOC 256

typedef __attribute__((ext_vector_type(8))) short bf16x8;
typedef __attribute__((ext_vector_type(4))) float f32x4;

__device__ __forceinline__ float sigf(float x) { return 1.0f / (1.0f + expf(-x)); }

__device__ __forceinline__ unsigned short f2bf(float f) {
    unsigned int u = __float_as_uint(f);
    u = (u + 0x7fffu + ((u >> 16) & 1u)) >> 16;   // RNE
    return (unsigned short)u;
}

// ---------------- bf16 MFMA GEMM (m97 structure: 128x128 tile, BK=32) ----------
// C[M,N] = A[M,K] @ W[N,K]^T + bias. A,W bf16 (K-contiguous); C fp32 or bf16.
template<bool RELU, bool OUT_BF16>
__global__ __launch_bounds__(256)
void gemm_bf16(const unsigned short* __restrict__ A, const unsigned short* __restrict__ W,
               const float* __restrict__ bias, void* __restrict__ C,
               int N, int K, int gx)
{
    __shared__ unsigned short As[128 * 32];
    __shared__ unsigned short Ws[128 * 32];
    const int tid = threadIdx.x;
    const int wid = tid >> 6, lane = tid & 63;

    // XCD-aware bijective swizzle (grid % 8 == 0 for all our launches)
    const int nwg = gridDim.x;
    const int cpx = nwg >> 3;
    const int bid = blockIdx.x;
    const int swz = (bid & 7) * cpx + (bid >> 3);
    const int bm = (swz / gx) * 128;
    const int bn = (swz % gx) * 128;

    const int wm = (wid >> 1) * 64, wn = (wid & 1) * 64;

    f32x4 acc[4][4];
#pragma unroll
    for (int i = 0; i < 4; i++)
#pragma unroll
        for (int j = 0; j < 4; j++) acc[i][j] = (f32x4){0.f, 0.f, 0.f, 0.f};

    const int l4 = lane >> 2;          // 0..15: row within 16-row chunk
    const int c8 = (lane & 3) * 8;     // 0,8,16,24: col start
    const int fr = lane & 15;          // fragment row/col
    const int fq = lane >> 4;          // 0..3: k-group / out row group

    for (int k0 = 0; k0 < K; k0 += 32) {
#pragma unroll
        for (int issue = 0; issue < 2; issue++) {
            const int chunk = issue * 4 + wid;          // 0..7
            const int row = chunk * 16 + l4;            // 0..127
            const unsigned short* ga = A + (size_t)(bm + row) * K + k0 + c8;
            const unsigned short* gw = W + (size_t)(bn + row) * K + k0 + c8;
            __builtin_amdgcn_global_load_lds(
                (const __attribute__((address_space(1))) void*)ga,
                (__attribute__((address_space(3))) void*)(As + chunk * 512), 16, 0, 0);
            __builtin_amdgcn_global_load_lds(
                (const __attribute__((address_space(1))) void*)gw,
                (__attribute__((address_space(3))) void*)(Ws + chunk * 512), 16, 0, 0);
        }
        __syncthreads();

        bf16x8 a[4], b[4];
#pragma unroll
        for (int m = 0; m < 4; m++)
            a[m] = *reinterpret_cast<const bf16x8*>(As + (wm + m * 16 + fr) * 32 + fq * 8);
#pragma unroll
        for (int n = 0; n < 4; n++)
            b[n] = *reinterpret_cast<const bf16x8*>(Ws + (wn + n * 16 + fr) * 32 + fq * 8);
#pragma unroll
        for (int m = 0; m < 4; m++)
#pragma unroll
            for (int n = 0; n < 4; n++)
                acc[m][n] = __builtin_amdgcn_mfma_f32_16x16x32_bf16(a[m], b[n], acc[m][n], 0, 0, 0);
        __syncthreads();
    }

#pragma unroll
    for (int m = 0; m < 4; m++) {
#pragma unroll
        for (int n = 0; n < 4; n++) {
            const int col = bn + wn + n * 16 + fr;
            const float bv = bias[col];
#pragma unroll
            for (int j = 0; j < 4; j++) {
                const int row = bm + wm + m * 16 + fq * 4 + j;
                float v = acc[m][n][j] + bv;
                if (RELU) v = fmaxf(v, 0.f);
                if (OUT_BF16)
                    ((unsigned short*)C)[(size_t)row * N + col] = f2bf(v);
                else
                    ((float*)C)[(size_t)row * N + col] = v;
            }
        }
    }
}

// ---------------- fp32 -> bf16 conversion ----------------
__global__ void cvt_bf16(const float* __restrict__ in, unsigned short* __restrict__ out, int n)
{
    int i = (blockIdx.x * blockDim.x + threadIdx.x) * 4;
    if (i >= n) return;
    float4 v = *reinterpret_cast<const float4*>(in + i);
    ushort4 o;
    o.x = f2bf(v.x); o.y = f2bf(v.y); o.z = f2bf(v.z); o.w = f2bf(v.w);
    *reinterpret_cast<ushort4*>(out + i) = o;
}

// ---------------- GEMV: out[n] = dot(x, Wm[n,:]) + bias ----------------
__global__ void gemv_bt(const float* __restrict__ x, const float* __restrict__ Wm,
                        const float* __restrict__ bias, float* __restrict__ out,
                        int N, int K)
{
    int wid = threadIdx.x >> 6;
    int lane = threadIdx.x & 63;
    int n = blockIdx.x * (blockDim.x >> 6) + wid;
    if (n >= N) return;
    const float* wr = Wm + (size_t)n * K;
    float s = 0.f;
    for (int p = 0; p < K; p += 256) {
        float4 xv = *reinterpret_cast<const float4*>(x + p + lane * 4);
        float4 wv = *reinterpret_cast<const float4*>(wr + p + lane * 4);
        s = fmaf(xv.x, wv.x, s); s = fmaf(xv.y, wv.y, s);
        s = fmaf(xv.z, wv.z, s); s = fmaf(xv.w, wv.w, s);
    }
#pragma unroll
    for (int off = 32; off; off >>= 1) s += __shfl_down(s, off);
    if (lane == 0) out[n] = s + (bias ? bias[n] : 0.f);
}

// ---------------- GRU combine kernels ----------------
// h1[v] = GRU(Gi[v], gh0, state); writes fp32 (for step2 h_prev) + bf16 (for K5 GEMM)
__global__ void h1_combine(const float* __restrict__ Gi, const float* __restrict__ gh0,
                           const float* __restrict__ state, float* __restrict__ h1,
                           unsigned short* __restrict__ h1b)
{
    int idx = blockIdx.x * blockDim.x + threadIdx.x;
    int v = idx >> 10, h = idx & (H - 1);
    const float* g = Gi + (size_t)v * H3;
    float r = sigf(g[h] + gh0[h]);
    float z = sigf(g[H + h] + gh0[H + h]);
    float n = tanhf(fmaf(r, gh0[2 * H + h], g[2 * H + h]));
    float v2 = (1.f - z) * n + z * state[h];
    h1[idx] = v2;
    h1b[idx] = f2bf(v2);
}

// rel step 2: write fp32 h2 (for step3) + bf16 h2b (for K7 GEMM)
__global__ void step2_rel(const int* __restrict__ toks,
                          const float* __restrict__ Gi, const float* __restrict__ gh1,
                          const float* __restrict__ h1,
                          float* __restrict__ out, unsigned short* __restrict__ outb)
{
    int idx = blockIdx.x * blockDim.x + threadIdx.x;
    int row = idx >> 10, h = idx & (H - 1);
    int t0 = toks[row * 3 + 0];
    int t1 = toks[row * 3 + 1];
    const float* g = Gi + (size_t)t1 * H3;
    const float* gh = gh1 + (size_t)t0 * H3;
    float r = sigf(g[h] + gh[h]);
    float z = sigf(g[H + h] + gh[H + h]);
    float n = tanhf(fmaf(r, gh[2 * H + h], g[2 * H + h]));
    float v = (1.f - z) * n + z * h1[(size_t)t0 * H + h];
    out[idx] = v;
    outb[idx] = f2bf(v);
}

// attr step 2 (final attr state): bf16 only (feeds K9 GEMM)
__global__ void step2_attr(const int* __restrict__ toks,
                           const float* __restrict__ Gi, const float* __restrict__ gh1,
                           const float* __restrict__ h1, unsigned short* __restrict__ outb)
{
    int idx = blockIdx.x * blockDim.x + threadIdx.x;
    int row = idx >> 10, h = idx & (H - 1);
    int t0 = toks[row * 2 + 0];
    int t1 = toks[row * 2 + 1];
    const float* g = Gi + (size_t)t1 * H3;
    const float* gh = gh1 + (size_t)t0 * H3;
    float r = sigf(g[h] + gh[h]);
    float z = sigf(g[H + h] + gh[H + h]);
    float n = tanhf(fmaf(r, gh[2 * H + h], g[2 * H + h]));
    outb[idx] = f2bf((1.f - z) * n + z * h1[(size_t)t0 * H + h]);
}

// rel step 3: bf16 clause rows [0, Nr)
__global__ void step3_rel(const int* __restrict__ toks,
                          const float* __restrict__ Gi, const float* __restrict__ gh2,
                          const float* __restrict__ h2, unsigned short* __restrict__ outb)
{
    int idx = blockIdx.x * blockDim.x + threadIdx.x;
    int row = idx >> 10, h = idx & (H - 1);
    int t2 = toks[row * 3 + 2];
    const float* g = Gi + (size_t)t2 * H3;
    const float* gh = gh2 + (size_t)row * H3;
    float r = sigf(g[h] + gh[h]);
    float z = sigf(g[H + h] + gh[H + h]);
    float n = tanhf(fmaf(r, gh[2 * H + h], g[2 * H + h]));
    outb[idx] = f2bf((1.f - z) * n + z * h2[idx]);
}

// ---------------- softmax + eps smoothing ----------------
__global__ void softmax_eps(const float* __restrict__ logits, const float* __restrict__ epsp,
                            float* __restrict__ out, int N)
{
    __shared__ float smax[16], ssum[16];
    int tid = threadIdx.x;
    int nw = blockDim.x >> 6;
    float m = -INFINITY;
    for (int i = tid; i < N; i += blockDim.x) m = fmaxf(m, logits[i]);
#pragma unroll
    for (int off = 32; off; off >>= 1) m = fmaxf(m, __shfl_down(m, off));
    if ((tid & 63) == 0) smax[tid >> 6] = m;
    __syncthreads();
    float M = smax[0];
    for (int i = 1; i < nw; i++) M = fmaxf(M, smax[i]);
    float s = 0.f;
    for (int i = tid; i < N; i += blockDim.x) s += expf(logits[i] - M);
#pragma unroll
    for (int off = 32; off; off >>= 1) s += __shfl_down(s, off);
    if ((tid & 63) == 0) ssum[tid >> 6] = s;
    __syncthreads();
    float S = 0.f;
    for (int i = 0; i < nw; i++) S += ssum[i];
    float e = epsp[0];
    float mul = (1.f - e) / S;
    float add = e / (float)N;
    for (int i = tid; i < N; i += blockDim.x) out[i] = expf(logits[i] - M) * mul + add;
}

extern "C" void kernel_launch(void* const* d_in, const int* in_sizes, int n_in,
                              void* d_out, int out_size, void* d_ws, size_t ws_size,
                              hipStream_t stream)
{
    const float* state       = (const float*)d_in[0];
    const int*   rel_tokens  = (const int*)d_in[1];
    const int*   attr_tokens = (const int*)d_in[2];
    const float* table       = (const float*)d_in[3];
    const float* W_emb       = (const float*)d_in[4];
    const float* b_emb       = (const float*)d_in[5];
    const float* W_ih        = (const float*)d_in[6];
    const float* W_hh        = (const float*)d_in[7];
    const float* b_ih        = (const float*)d_in[8];
    const float* b_hh        = (const float*)d_in[9];
    const float* W1          = (const float*)d_in[10];
    const float* b1          = (const float*)d_in[11];
    const float* W2          = (const float*)d_in[12];
    const float* b2          = (const float*)d_in[13];
    const float* W3          = (const float*)d_in[14];
    // d_in[15] = b3: softmax-invariant, skipped.
    const float* eps         = (const float*)d_in[16];

    const int Nr = in_sizes[1] / 3;   // 4096
    const int Na = in_sizes[2] / 2;   // 4096
    const int Ntot = Nr + Na;         // 8192

    // fp32 workspace
    float* ws     = (float*)d_ws;
    float* Gi     = ws;                               // 256*3072
    float* gh0    = Gi + NVOC * H3;                   // 3072
    float* h1     = gh0 + H3;                         // 256*1024
    float* gh1    = h1 + NVOC * H;                    // 256*3072
    float* h2     = gh1 + NVOC * H3;                  // Nr*1024
    float* gh2    = h2 + (size_t)Nr * H;              // Nr*3072  (48 MB)
    float* x2     = gh2;                              // alias: gh2 dead after step3
    float* logits = gh2 + (size_t)Nr * H3;            // Ntot
    // bf16 workspace
    unsigned short* W_hhb   = (unsigned short*)(logits + Ntot);
    unsigned short* W1b     = W_hhb + (size_t)H3 * H;
    unsigned short* W2b     = W1b + (size_t)H * H;
    unsigned short* W_embb  = W2b + (size_t)H * H;
    unsigned short* W_ihb   = W_embb + (size_t)H * H;
    unsigned short* tableb  = W_ihb + (size_t)H3 * H;
    unsigned short* embb    = tableb + (size_t)NVOC * H;
    unsigned short* h1b     = embb + (size_t)NVOC * H;
    unsigned short* h2b     = h1b + (size_t)NVOC * H;       // Nr*1024
    unsigned short* clauseb = h2b + (size_t)Nr * H;         // Ntot*1024
    unsigned short* x1b     = clauseb + (size_t)Ntot * H;   // Ntot*1024

    // W0: weight/table conversions (independent of everything else)
    cvt_bf16<<<(H3 * H / 4 + 255) / 256, 256, 0, stream>>>(W_hh, W_hhb, H3 * H);
    cvt_bf16<<<(H3 * H / 4 + 255) / 256, 256, 0, stream>>>(W_ih, W_ihb, H3 * H);
    cvt_bf16<<<(H * H / 4 + 255) / 256, 256, 0, stream>>>(W1, W1b, H * H);
    cvt_bf16<<<(H * H / 4 + 255) / 256, 256, 0, stream>>>(W2, W2b, H * H);
    cvt_bf16<<<(H * H / 4 + 255) / 256, 256, 0, stream>>>(W_emb, W_embb, H * H);
    cvt_bf16<<<(NVOC * H / 4 + 255) / 256, 256, 0, stream>>>(table, tableb, NVOC * H);

    // K1: embb = table @ W_emb^T + b_emb               [256,1024]  bf16 MFMA
    gemm_bf16<false, true><<<(H / 128) * (NVOC / 128), 256, 0, stream>>>(
        tableb, W_embb, b_emb, embb, H, H, H / 128);
    // K2: Gi = emb @ W_ih^T + b_ih                     [256,3072]  bf16 MFMA
    gemm_bf16<false, false><<<(H3 / 128) * (NVOC / 128), 256, 0, stream>>>(
        embb, W_ihb, b_ih, Gi, H3, H, H3 / 128);
    // K3: gh0 = state @ W_hh^T + b_hh                  [3072]
    gemv_bt<<<H3 / 4, 256, 0, stream>>>(state, W_hh, b_hh, gh0, H3, H);
    // K4: h1[v] for the 256 distinct tokens (fp32 + bf16)
    h1_combine<<<NVOC * H / 256, 256, 0, stream>>>(Gi, gh0, state, h1, h1b);
    // K5: gh1 = h1 @ W_hh^T + b_hh                     [256,3072]  bf16 MFMA
    gemm_bf16<false, false><<<(H3 / 128) * (NVOC / 128), 256, 0, stream>>>(
        h1b, W_hhb, b_hh, gh1, H3, H, H3 / 128);
    // K6a: rel step 2 -> h2 (fp32) + h2b (bf16)
    step2_rel<<<Nr * (H / 256), 256, 0, stream>>>(rel_tokens, Gi, gh1, h1, h2, h2b);
    // K6b: attr step 2 -> clauseb rows [Nr, Nr+Na)
    step2_attr<<<Na * (H / 256), 256, 0, stream>>>(attr_tokens, Gi, gh1, h1,
                                                   clauseb + (size_t)Nr * H);
    // K7: gh2 = h2 @ W_hh^T + b_hh                     [4096,3072]  bf16 MFMA
    gemm_bf16<false, false><<<(H3 / 128) * (Nr / 128), 256, 0, stream>>>(
        h2b, W_hhb, b_hh, gh2, H3, H, H3 / 128);
    // K8: rel step 3 -> clauseb rows [0, Nr)
    step3_rel<<<Nr * (H / 256), 256, 0, stream>>>(rel_tokens, Gi, gh2, h2, clauseb);
    // K9: x1b = relu(clause @ W1^T + b1)               [8192,1024]  bf16 MFMA
    gemm_bf16<true, true><<<(H / 128) * (Ntot / 128), 256, 0, stream>>>(
        clauseb, W1b, b1, x1b, H, H, H / 128);
    // K10: x2 = relu(x1 @ W2^T + b2)                   [8192,1024]  bf16 MFMA
    gemm_bf16<true, false><<<(H / 128) * (Ntot / 128), 256, 0, stream>>>(
        x1b, W2b, b2, x2, H, H, H / 128);
    // K11: logits[n] = dot(x2[n], W3)                  [8192]
    gemv_bt<<<Ntot / 4, 256, 0, stream>>>(W3, x2, nullptr, logits, Ntot, H);
    // K12: softmax + eps smoothing -> d_out
    softmax_eps<<<1, 1024, 0, stream>>>(logits, eps, (float*)d_out, Ntot);
}

// Round 4
// 337.790 us; speedup vs baseline: 3.0577x; 1.0449x over previous
//
#include <hip/hip_runtime.h>
#include <math.h>

#define H 1024
#define H3 3072
#define NVOC 256

typedef __attribute__((ext_vector_type(8))) short bf16x8;
typedef __attribute__((ext_vector_type(4))) float f32x4;

__device__ __forceinline__ float sigf(float x) { return 1.0f / (1.0f + expf(-x)); }

__device__ __forceinline__ unsigned short f2bf(float f) {
    unsigned int u = __float_as_uint(f);
    u = (u + 0x7fffu + ((u >> 16) & 1u)) >> 16;   // RNE
    return (unsigned short)u;
}
__device__ __forceinline__ float bf2f(unsigned short u) {
    return __uint_as_float(((unsigned int)u) << 16);
}

// ---------------- bf16 MFMA GEMM (m97 structure: 128x128 tile, BK=32) ----------
// C[M,N] = A[M,K] @ W[N,K]^T + bias.
// OUT_MODE: 0 = fp32 C, 1 = bf16 C, 2 = fused dot with w3 -> atomicAdd logits (no C write)
template<bool RELU, int OUT_MODE>
__global__ __launch_bounds__(256)
void gemm_bf16(const unsigned short* __restrict__ A, const unsigned short* __restrict__ W,
               const float* __restrict__ bias, void* __restrict__ C,
               int N, int K, int gx,
               const float* __restrict__ w3, float* __restrict__ logits)
{
    __shared__ unsigned short As[128 * 32];
    __shared__ unsigned short Ws[128 * 32];
    const int tid = threadIdx.x;
    const int wid = tid >> 6, lane = tid & 63;

    // XCD-aware bijective swizzle (grid % 8 == 0 for all our launches)
    const int nwg = gridDim.x;
    const int cpx = nwg >> 3;
    const int bid = blockIdx.x;
    const int swz = (bid & 7) * cpx + (bid >> 3);
    const int bm = (swz / gx) * 128;
    const int bn = (swz % gx) * 128;

    const int wm = (wid >> 1) * 64, wn = (wid & 1) * 64;

    f32x4 acc[4][4];
#pragma unroll
    for (int i = 0; i < 4; i++)
#pragma unroll
        for (int j = 0; j < 4; j++) acc[i][j] = (f32x4){0.f, 0.f, 0.f, 0.f};

    const int l4 = lane >> 2;          // 0..15: row within 16-row chunk
    const int c8 = (lane & 3) * 8;     // 0,8,16,24: col start
    const int fr = lane & 15;          // fragment row/col
    const int fq = lane >> 4;          // 0..3: k-group / out row group

    for (int k0 = 0; k0 < K; k0 += 32) {
#pragma unroll
        for (int issue = 0; issue < 2; issue++) {
            const int chunk = issue * 4 + wid;          // 0..7
            const int row = chunk * 16 + l4;            // 0..127
            const unsigned short* ga = A + (size_t)(bm + row) * K + k0 + c8;
            const unsigned short* gw = W + (size_t)(bn + row) * K + k0 + c8;
            __builtin_amdgcn_global_load_lds(
                (const __attribute__((address_space(1))) void*)ga,
                (__attribute__((address_space(3))) void*)(As + chunk * 512), 16, 0, 0);
            __builtin_amdgcn_global_load_lds(
                (const __attribute__((address_space(1))) void*)gw,
                (__attribute__((address_space(3))) void*)(Ws + chunk * 512), 16, 0, 0);
        }
        __syncthreads();

        bf16x8 a[4], b[4];
#pragma unroll
        for (int m = 0; m < 4; m++)
            a[m] = *reinterpret_cast<const bf16x8*>(As + (wm + m * 16 + fr) * 32 + fq * 8);
#pragma unroll
        for (int n = 0; n < 4; n++)
            b[n] = *reinterpret_cast<const bf16x8*>(Ws + (wn + n * 16 + fr) * 32 + fq * 8);
#pragma unroll
        for (int m = 0; m < 4; m++)
#pragma unroll
            for (int n = 0; n < 4; n++)
                acc[m][n] = __builtin_amdgcn_mfma_f32_16x16x32_bf16(a[m], b[n], acc[m][n], 0, 0, 0);
        __syncthreads();
    }

    if (OUT_MODE == 2) {
        // fused: logits[row] += sum_col relu(acc+bias) * w3[col]
        float rs[4][4];
#pragma unroll
        for (int m = 0; m < 4; m++)
#pragma unroll
            for (int j = 0; j < 4; j++) rs[m][j] = 0.f;
#pragma unroll
        for (int n = 0; n < 4; n++) {
            const int col = bn + wn + n * 16 + fr;
            const float bv = bias[col];
            const float wv = w3[col];
#pragma unroll
            for (int m = 0; m < 4; m++)
#pragma unroll
                for (int j = 0; j < 4; j++) {
                    float v = acc[m][n][j] + bv;
                    if (RELU) v = fmaxf(v, 0.f);
                    rs[m][j] = fmaf(v, wv, rs[m][j]);
                }
        }
#pragma unroll
        for (int m = 0; m < 4; m++)
#pragma unroll
            for (int j = 0; j < 4; j++) {
                float s = rs[m][j];
                s += __shfl_xor(s, 1); s += __shfl_xor(s, 2);
                s += __shfl_xor(s, 4); s += __shfl_xor(s, 8);
                if (fr == 0) atomicAdd(logits + bm + wm + m * 16 + fq * 4 + j, s);
            }
    } else {
#pragma unroll
        for (int m = 0; m < 4; m++) {
#pragma unroll
            for (int n = 0; n < 4; n++) {
                const int col = bn + wn + n * 16 + fr;
                const float bv = bias[col];
#pragma unroll
                for (int j = 0; j < 4; j++) {
                    const int row = bm + wm + m * 16 + fq * 4 + j;
                    float v = acc[m][n][j] + bv;
                    if (RELU) v = fmaxf(v, 0.f);
                    if (OUT_MODE == 1)
                        ((unsigned short*)C)[(size_t)row * N + col] = f2bf(v);
                    else
                        ((float*)C)[(size_t)row * N + col] = v;
                }
            }
        }
    }
}

// ---------------- fused fp32 -> bf16 conversion of all weights ----------------
__global__ void cvt_all(const float* __restrict__ W_hh, const float* __restrict__ W_ih,
                        const float* __restrict__ W1, const float* __restrict__ W2,
                        const float* __restrict__ W_emb, const float* __restrict__ table,
                        unsigned short* __restrict__ W_hhb, unsigned short* __restrict__ W_ihb,
                        unsigned short* __restrict__ W1b, unsigned short* __restrict__ W2b,
                        unsigned short* __restrict__ W_embb, unsigned short* __restrict__ tableb)
{
    const int C1 = H3 * H, C2 = H * H, C3 = NVOC * H;
    int off = (blockIdx.x * blockDim.x + threadIdx.x) * 4;
    const float* src; unsigned short* dst;
    if (off < C1)               { src = W_hh;  dst = W_hhb; }
    else if ((off -= C1) < C1)  { src = W_ih;  dst = W_ihb; }
    else if ((off -= C1) < C2)  { src = W1;    dst = W1b; }
    else if ((off -= C2) < C2)  { src = W2;    dst = W2b; }
    else if ((off -= C2) < C2)  { src = W_emb; dst = W_embb; }
    else if ((off -= C2) < C3)  { src = table; dst = tableb; }
    else return;
    float4 v = *reinterpret_cast<const float4*>(src + off);
    ushort4 o;
    o.x = f2bf(v.x); o.y = f2bf(v.y); o.z = f2bf(v.z); o.w = f2bf(v.w);
    *reinterpret_cast<ushort4*>(dst + off) = o;
}

// ---------------- GEMV: out[n] = dot(x, Wm[n,:]) + bias  (bf16 weight rows) ----
__global__ void gemv_bf16w(const float* __restrict__ x, const unsigned short* __restrict__ Wm,
                           const float* __restrict__ bias, float* __restrict__ out,
                           int N, int K)
{
    int wid = threadIdx.x >> 6;
    int lane = threadIdx.x & 63;
    int n = blockIdx.x * (blockDim.x >> 6) + wid;
    if (n >= N) return;
    const unsigned short* wr = Wm + (size_t)n * K;
    float s = 0.f;
    for (int p = 0; p < K; p += 256) {
        float4 xv = *reinterpret_cast<const float4*>(x + p + lane * 4);
        ushort4 wv = *reinterpret_cast<const ushort4*>(wr + p + lane * 4);
        s = fmaf(xv.x, bf2f(wv.x), s); s = fmaf(xv.y, bf2f(wv.y), s);
        s = fmaf(xv.z, bf2f(wv.z), s); s = fmaf(xv.w, bf2f(wv.w), s);
    }
#pragma unroll
    for (int off = 32; off; off >>= 1) s += __shfl_down(s, off);
    if (lane == 0) out[n] = s + (bias ? bias[n] : 0.f);
}

// ---------------- GRU combine kernels ----------------
// h1[v] = GRU(Gi[v], gh0, state); writes fp32 (step2 h_prev) + bf16 (K5 A operand)
__global__ void h1_combine(const float* __restrict__ Gi, const float* __restrict__ gh0,
                           const float* __restrict__ state, float* __restrict__ h1,
                           unsigned short* __restrict__ h1b)
{
    int idx = blockIdx.x * blockDim.x + threadIdx.x;
    int v = idx >> 10, h = idx & (H - 1);
    const float* g = Gi + (size_t)v * H3;
    float r = sigf(g[h] + gh0[h]);
    float z = sigf(g[H + h] + gh0[H + h]);
    float n = tanhf(fmaf(r, gh0[2 * H + h], g[2 * H + h]));
    float v2 = (1.f - z) * n + z * state[h];
    h1[idx] = v2;
    h1b[idx] = f2bf(v2);
}

// step 2 for BOTH branches: rows [0,Nr) = rel -> h2b; rows [Nr,Ntot) = attr -> attr_out
__global__ void step2_both(const int* __restrict__ rel, const int* __restrict__ attr, int Nr,
                           const float* __restrict__ Gi, const float* __restrict__ gh1,
                           const float* __restrict__ h1,
                           unsigned short* __restrict__ h2b, unsigned short* __restrict__ attr_out)
{
    int idx = blockIdx.x * blockDim.x + threadIdx.x;
    int row = idx >> 10, h = idx & (H - 1);
    int t0, t1, orow = row;
    unsigned short* dst;
    if (row < Nr) { t0 = rel[row * 3 + 0]; t1 = rel[row * 3 + 1]; dst = h2b; }
    else { orow = row - Nr; t0 = attr[orow * 2 + 0]; t1 = attr[orow * 2 + 1]; dst = attr_out; }
    const float* g = Gi + (size_t)t1 * H3;
    const float* gh = gh1 + (size_t)t0 * H3;
    float r = sigf(g[h] + gh[h]);
    float z = sigf(g[H + h] + gh[H + h]);
    float n = tanhf(fmaf(r, gh[2 * H + h], g[2 * H + h]));
    float v = (1.f - z) * n + z * h1[(size_t)t0 * H + h];
    dst[(size_t)orow * H + h] = f2bf(v);
}

// rel step 3: reads bf16 gh2b/h2b -> bf16 clause rows [0, Nr)
__global__ void step3_rel(const int* __restrict__ toks,
                          const float* __restrict__ Gi, const unsigned short* __restrict__ gh2b,
                          const unsigned short* __restrict__ h2b, unsigned short* __restrict__ outb)
{
    int idx = blockIdx.x * blockDim.x + threadIdx.x;
    int row = idx >> 10, h = idx & (H - 1);
    int t2 = toks[row * 3 + 2];
    const float* g = Gi + (size_t)t2 * H3;
    const unsigned short* gh = gh2b + (size_t)row * H3;
    float r = sigf(g[h] + bf2f(gh[h]));
    float z = sigf(g[H + h] + bf2f(gh[H + h]));
    float n = tanhf(fmaf(r, bf2f(gh[2 * H + h]), g[2 * H + h]));
    outb[idx] = f2bf((1.f - z) * n + z * bf2f(h2b[idx]));
}

// ---------------- softmax + eps smoothing ----------------
__global__ void softmax_eps(const float* __restrict__ logits, const float* __restrict__ epsp,
                            float* __restrict__ out, int N)
{
    __shared__ float smax[16], ssum[16];
    int tid = threadIdx.x;
    int nw = blockDim.x >> 6;
    float m = -INFINITY;
    for (int i = tid; i < N; i += blockDim.x) m = fmaxf(m, logits[i]);
#pragma unroll
    for (int off = 32; off; off >>= 1) m = fmaxf(m, __shfl_down(m, off));
    if ((tid & 63) == 0) smax[tid >> 6] = m;
    __syncthreads();
    float M = smax[0];
    for (int i = 1; i < nw; i++) M = fmaxf(M, smax[i]);
    float s = 0.f;
    for (int i = tid; i < N; i += blockDim.x) s += expf(logits[i] - M);
#pragma unroll
    for (int off = 32; off; off >>= 1) s += __shfl_down(s, off);
    if ((tid & 63) == 0) ssum[tid >> 6] = s;
    __syncthreads();
    float S = 0.f;
    for (int i = 0; i < nw; i++) S += ssum[i];
    float e = epsp[0];
    float mul = (1.f - e) / S;
    float add = e / (float)N;
    for (int i = tid; i < N; i += blockDim.x) out[i] = expf(logits[i] - M) * mul + add;
}

extern "C" void kernel_launch(void* const* d_in, const int* in_sizes, int n_in,
                              void* d_out, int out_size, void* d_ws, size_t ws_size,
                              hipStream_t stream)
{
    const float* state       = (const float*)d_in[0];
    const int*   rel_tokens  = (const int*)d_in[1];
    const int*   attr_tokens = (const int*)d_in[2];
    const float* table       = (const float*)d_in[3];
    const float* W_emb       = (const float*)d_in[4];
    const float* b_emb       = (const float*)d_in[5];
    const float* W_ih        = (const float*)d_in[6];
    const float* W_hh        = (const float*)d_in[7];
    const float* b_ih        = (const float*)d_in[8];
    const float* b_hh        = (const float*)d_in[9];
    const float* W1          = (const float*)d_in[10];
    const float* b1          = (const float*)d_in[11];
    const float* W2          = (const float*)d_in[12];
    const float* b2          = (const float*)d_in[13];
    const float* W3          = (const float*)d_in[14];
    // d_in[15] = b3: softmax-invariant, skipped.
    const float* eps         = (const float*)d_in[16];

    const int Nr = in_sizes[1] / 3;   // 4096
    const int Na = in_sizes[2] / 2;   // 4096
    const int Ntot = Nr + Na;         // 8192

    // fp32 workspace
    float* ws     = (float*)d_ws;
    float* Gi     = ws;                               // 256*3072
    float* gh0    = Gi + NVOC * H3;                   // 3072
    float* h1     = gh0 + H3;                         // 256*1024
    float* gh1    = h1 + NVOC * H;                    // 256*3072
    float* logits = gh1 + NVOC * H3;                  // Ntot
    // bf16 workspace
    unsigned short* W_hhb   = (unsigned short*)(logits + Ntot);
    unsigned short* W_ihb   = W_hhb + (size_t)H3 * H;
    unsigned short* W1b     = W_ihb + (size_t)H3 * H;
    unsigned short* W2b     = W1b + (size_t)H * H;
    unsigned short* W_embb  = W2b + (size_t)H * H;
    unsigned short* tableb  = W_embb + (size_t)H * H;
    unsigned short* embb    = tableb + (size_t)NVOC * H;
    unsigned short* h1b     = embb + (size_t)NVOC * H;
    unsigned short* h2b     = h1b + (size_t)NVOC * H;       // Nr*1024
    unsigned short* gh2b    = h2b + (size_t)Nr * H;         // Nr*3072
    unsigned short* clauseb = gh2b + (size_t)Nr * H3;       // Ntot*1024
    unsigned short* x1b     = clauseb + (size_t)Ntot * H;   // Ntot*1024

    // W0: all weight/table conversions in one launch
    {
        const int total = 2 * H3 * H + 3 * H * H + NVOC * H;
        cvt_all<<<(total / 4 + 255) / 256, 256, 0, stream>>>(
            W_hh, W_ih, W1, W2, W_emb, table,
            W_hhb, W_ihb, W1b, W2b, W_embb, tableb);
    }
    // zero logits accumulator (fused K10 dot uses atomics)
    hipMemsetAsync(logits, 0, Ntot * sizeof(float), stream);

    // K1: embb = table @ W_emb^T + b_emb               [256,1024]  bf16
    gemm_bf16<false, 1><<<(H / 128) * (NVOC / 128), 256, 0, stream>>>(
        tableb, W_embb, b_emb, embb, H, H, H / 128, nullptr, nullptr);
    // K2: Gi = emb @ W_ih^T + b_ih                     [256,3072]
    gemm_bf16<false, 0><<<(H3 / 128) * (NVOC / 128), 256, 0, stream>>>(
        embb, W_ihb, b_ih, Gi, H3, H, H3 / 128, nullptr, nullptr);
    // K3: gh0 = state @ W_hh^T + b_hh                  [3072] (bf16 weights)
    gemv_bf16w<<<H3 / 4, 256, 0, stream>>>(state, W_hhb, b_hh, gh0, H3, H);
    // K4: h1[v] for the 256 distinct tokens (fp32 + bf16)
    h1_combine<<<NVOC * H / 256, 256, 0, stream>>>(Gi, gh0, state, h1, h1b);
    // K5: gh1 = h1 @ W_hh^T + b_hh                     [256,3072]
    gemm_bf16<false, 0><<<(H3 / 128) * (NVOC / 128), 256, 0, stream>>>(
        h1b, W_hhb, b_hh, gh1, H3, H, H3 / 128, nullptr, nullptr);
    // K6: step 2 both branches -> h2b + clauseb[Nr:]
    step2_both<<<Ntot * (H / 256), 256, 0, stream>>>(rel_tokens, attr_tokens, Nr,
                                                     Gi, gh1, h1, h2b,
                                                     clauseb + (size_t)Nr * H);
    // K7: gh2b = h2 @ W_hh^T + b_hh                    [4096,3072]  bf16 out
    gemm_bf16<false, 1><<<(H3 / 128) * (Nr / 128), 256, 0, stream>>>(
        h2b, W_hhb, b_hh, gh2b, H3, H, H3 / 128, nullptr, nullptr);
    // K8: rel step 3 -> clauseb rows [0, Nr)
    step3_rel<<<Nr * (H / 256), 256, 0, stream>>>(rel_tokens, Gi, gh2b, h2b, clauseb);
    // K9: x1b = relu(clause @ W1^T + b1)               [8192,1024]  bf16 out
    gemm_bf16<true, 1><<<(H / 128) * (Ntot / 128), 256, 0, stream>>>(
        clauseb, W1b, b1, x1b, H, H, H / 128, nullptr, nullptr);
    // K10+K11 fused: logits[row] += relu(x1 @ W2^T + b2) . W3   [8192]
    gemm_bf16<true, 2><<<(H / 128) * (Ntot / 128), 256, 0, stream>>>(
        x1b, W2b, b2, nullptr, H, H, H / 128, W3, logits);
    // K12: softmax + eps smoothing -> d_out
    softmax_eps<<<1, 1024, 0, stream>>>(logits, eps, (float*)d_out, Ntot);
}

// Round 5
// 319.136 us; speedup vs baseline: 3.2365x; 1.0585x over previous
//
#include <hip/hip_runtime.h>
#include <math.h>

#define H 1024
#define H3 3072
#define NVOC 256

typedef __attribute__((ext_vector_type(8))) short bf16x8;
typedef __attribute__((ext_vector_type(4))) float f32x4;

__device__ __forceinline__ float sigf(float x) { return 1.0f / (1.0f + expf(-x)); }

__device__ __forceinline__ unsigned short f2bf(float f) {
    unsigned int u = __float_as_uint(f);
    u = (u + 0x7fffu + ((u >> 16) & 1u)) >> 16;   // RNE
    return (unsigned short)u;
}
__device__ __forceinline__ float bf2f(unsigned short u) {
    return __uint_as_float(((unsigned int)u) << 16);
}

// ---------------- bf16 MFMA GEMM, 4-deep pipelined (counted vmcnt) -------------
// C[M,N] = A[M,K_chunk] @ W[N,K_chunk]^T (+ bias). 128x128 tile, BK=32, 4 waves.
// LDS: 4-buffer ring (64 KB). Loop: vmcnt(8) -> barrier -> stage t+3 -> compute t.
// XOR chunk swizzle (chunk ^= row&3) on stage-source AND read addr (4-way conflicts).
// OUT_MODE: 0 fp32 C (+bias), 1 bf16 C (+bias), 2 fused dot w3 -> atomicAdd logits,
//           3 fp32 atomicAdd into C (split-K; bias prefilled by caller)
template<bool RELU, int OUT_MODE>
__global__ __launch_bounds__(256)
void gemm_bf16(const unsigned short* __restrict__ A, const unsigned short* __restrict__ W,
               const float* __restrict__ bias, void* __restrict__ C,
               int N, int K, int gx, int Kc,
               const float* __restrict__ w3, float* __restrict__ logits)
{
    __shared__ unsigned short As[4][128 * 32];
    __shared__ unsigned short Ws[4][128 * 32];
    const int tid = threadIdx.x;
    const int wid = tid >> 6, lane = tid & 63;

    // XCD-aware bijective swizzle over tile space (gridDim.x % 8 == 0 everywhere)
    const int nwg = gridDim.x;
    const int cpx = nwg >> 3;
    const int bid = blockIdx.x;
    const int swz = (bid & 7) * cpx + (bid >> 3);
    const int bm = (swz / gx) * 128;
    const int bn = (swz % gx) * 128;
    const int k_base = blockIdx.y * Kc;     // split-K chunk
    const int nt = Kc >> 5;                 // K-tiles of 32

    const int wm = (wid >> 1) * 64, wn = (wid & 1) * 64;
    const int fr = lane & 15;               // fragment row/col
    const int fq = lane >> 4;               // k-subchunk
    const int perm = fq ^ (fr & 3);         // swizzled chunk for reads

    f32x4 acc[4][4];
#pragma unroll
    for (int i = 0; i < 4; i++)
#pragma unroll
        for (int j = 0; j < 4; j++) acc[i][j] = (f32x4){0.f, 0.f, 0.f, 0.f};

    // staging: thread t covers LDS bytes t*16 (+issue*4096); logical row = tid>>2,
    // physical chunk = tid&3 holds logical chunk (tid&3)^(row&3)  [XOR involution]
    const int srow = tid >> 2;
    const int schunk = (tid & 3) ^ (srow & 3);
    const unsigned short* aS = A + (size_t)(bm + srow) * K + k_base + schunk * 8;
    const unsigned short* wS = W + (size_t)(bn + srow) * K + k_base + schunk * 8;
    const size_t rstep = (size_t)64 * K;    // +64 rows

    auto stage = [&](int b, int t) {
        const unsigned short* a0 = aS + t * 32;
        const unsigned short* w0 = wS + t * 32;
        __builtin_amdgcn_global_load_lds(
            (const __attribute__((address_space(1))) void*)a0,
            (__attribute__((address_space(3))) void*)(&As[b][wid * 512]), 16, 0, 0);
        __builtin_amdgcn_global_load_lds(
            (const __attribute__((address_space(1))) void*)(a0 + rstep),
            (__attribute__((address_space(3))) void*)(&As[b][2048 + wid * 512]), 16, 0, 0);
        __builtin_amdgcn_global_load_lds(
            (const __attribute__((address_space(1))) void*)w0,
            (__attribute__((address_space(3))) void*)(&Ws[b][wid * 512]), 16, 0, 0);
        __builtin_amdgcn_global_load_lds(
            (const __attribute__((address_space(1))) void*)(w0 + rstep),
            (__attribute__((address_space(3))) void*)(&Ws[b][2048 + wid * 512]), 16, 0, 0);
    };

    // prologue: 3 tiles in flight
    stage(0, 0);
    if (nt > 1) stage(1, 1);
    if (nt > 2) stage(2, 2);

    for (int t = 0; t < nt; ++t) {
        // wait for tile t only (2 newer tiles stay in flight), then rendezvous
        if (t + 2 < nt)      asm volatile("s_waitcnt vmcnt(8)" ::: "memory");
        else if (t + 1 < nt) asm volatile("s_waitcnt vmcnt(4)" ::: "memory");
        else                 asm volatile("s_waitcnt vmcnt(0)" ::: "memory");
        __builtin_amdgcn_s_barrier();
        __builtin_amdgcn_sched_barrier(0);
        if (t + 3 < nt) stage((t + 3) & 3, t + 3);

        const unsigned short* as = &As[t & 3][0];
        const unsigned short* ws = &Ws[t & 3][0];
        bf16x8 a[4], b[4];
#pragma unroll
        for (int m = 0; m < 4; m++)
            a[m] = *reinterpret_cast<const bf16x8*>(as + (wm + m * 16 + fr) * 32 + perm * 8);
#pragma unroll
        for (int n = 0; n < 4; n++)
            b[n] = *reinterpret_cast<const bf16x8*>(ws + (wn + n * 16 + fr) * 32 + perm * 8);
        __builtin_amdgcn_s_setprio(1);
#pragma unroll
        for (int m = 0; m < 4; m++)
#pragma unroll
            for (int n = 0; n < 4; n++)
                acc[m][n] = __builtin_amdgcn_mfma_f32_16x16x32_bf16(a[m], b[n], acc[m][n], 0, 0, 0);
        __builtin_amdgcn_s_setprio(0);
    }

    if (OUT_MODE == 2) {
        // fused: logits[row] += sum_col relu(acc+bias) * w3[col]
        float rs[4][4];
#pragma unroll
        for (int m = 0; m < 4; m++)
#pragma unroll
            for (int j = 0; j < 4; j++) rs[m][j] = 0.f;
#pragma unroll
        for (int n = 0; n < 4; n++) {
            const int col = bn + wn + n * 16 + fr;
            const float bv = bias[col];
            const float wv = w3[col];
#pragma unroll
            for (int m = 0; m < 4; m++)
#pragma unroll
                for (int j = 0; j < 4; j++) {
                    float v = acc[m][n][j] + bv;
                    if (RELU) v = fmaxf(v, 0.f);
                    rs[m][j] = fmaf(v, wv, rs[m][j]);
                }
        }
#pragma unroll
        for (int m = 0; m < 4; m++)
#pragma unroll
            for (int j = 0; j < 4; j++) {
                float s = rs[m][j];
                s += __shfl_xor(s, 1); s += __shfl_xor(s, 2);
                s += __shfl_xor(s, 4); s += __shfl_xor(s, 8);
                if (fr == 0) atomicAdd(logits + bm + wm + m * 16 + fq * 4 + j, s);
            }
    } else if (OUT_MODE == 3) {
        float* Cf = (float*)C;
#pragma unroll
        for (int m = 0; m < 4; m++)
#pragma unroll
            for (int n = 0; n < 4; n++) {
                const int col = bn + wn + n * 16 + fr;
#pragma unroll
                for (int j = 0; j < 4; j++) {
                    const int row = bm + wm + m * 16 + fq * 4 + j;
                    atomicAdd(Cf + (size_t)row * N + col, acc[m][n][j]);
                }
            }
    } else {
#pragma unroll
        for (int m = 0; m < 4; m++) {
#pragma unroll
            for (int n = 0; n < 4; n++) {
                const int col = bn + wn + n * 16 + fr;
                const float bv = bias[col];
#pragma unroll
                for (int j = 0; j < 4; j++) {
                    const int row = bm + wm + m * 16 + fq * 4 + j;
                    float v = acc[m][n][j] + bv;
                    if (RELU) v = fmaxf(v, 0.f);
                    if (OUT_MODE == 1)
                        ((unsigned short*)C)[(size_t)row * N + col] = f2bf(v);
                    else
                        ((float*)C)[(size_t)row * N + col] = v;
                }
            }
        }
    }
}

// ---------------- fused fp32 -> bf16 conversion of all weights ----------------
__global__ void cvt_all(const float* __restrict__ W_hh, const float* __restrict__ W_ih,
                        const float* __restrict__ W1, const float* __restrict__ W2,
                        const float* __restrict__ W_emb, const float* __restrict__ table,
                        unsigned short* __restrict__ W_hhb, unsigned short* __restrict__ W_ihb,
                        unsigned short* __restrict__ W1b, unsigned short* __restrict__ W2b,
                        unsigned short* __restrict__ W_embb, unsigned short* __restrict__ tableb)
{
    const int C1 = H3 * H, C2 = H * H, C3 = NVOC * H;
    int off = (blockIdx.x * blockDim.x + threadIdx.x) * 4;
    const float* src; unsigned short* dst;
    if (off < C1)               { src = W_hh;  dst = W_hhb; }
    else if ((off -= C1) < C1)  { src = W_ih;  dst = W_ihb; }
    else if ((off -= C1) < C2)  { src = W1;    dst = W1b; }
    else if ((off -= C2) < C2)  { src = W2;    dst = W2b; }
    else if ((off -= C2) < C2)  { src = W_emb; dst = W_embb; }
    else if ((off -= C2) < C3)  { src = table; dst = tableb; }
    else return;
    float4 v = *reinterpret_cast<const float4*>(src + off);
    ushort4 o;
    o.x = f2bf(v.x); o.y = f2bf(v.y); o.z = f2bf(v.z); o.w = f2bf(v.w);
    *reinterpret_cast<ushort4*>(dst + off) = o;
}

// ---------------- bias prefill for split-K accumulators + logits zero ----------
__global__ void prefill(const float* __restrict__ b_emb, const float* __restrict__ b_ih,
                        const float* __restrict__ b_hh,
                        float* __restrict__ emb32, float* __restrict__ Gi,
                        float* __restrict__ gh1, float* __restrict__ logits, int Ntot)
{
    const int E = NVOC * H, G = NVOC * H3;
    int i = blockIdx.x * blockDim.x + threadIdx.x;
    if (i < E)                { emb32[i] = b_emb[i & (H - 1)]; return; }
    if ((i -= E) < G)         { Gi[i] = b_ih[i % H3]; return; }
    if ((i -= G) < G)         { gh1[i] = b_hh[i % H3]; return; }
    if ((i -= G) < Ntot)      logits[i] = 0.f;
}

// ---------------- fp32 -> bf16 (emb) ----------------
__global__ void cvt_emb(const float* __restrict__ in, unsigned short* __restrict__ out)
{
    int i = (blockIdx.x * blockDim.x + threadIdx.x) * 4;
    float4 v = *reinterpret_cast<const float4*>(in + i);
    ushort4 o;
    o.x = f2bf(v.x); o.y = f2bf(v.y); o.z = f2bf(v.z); o.w = f2bf(v.w);
    *reinterpret_cast<ushort4*>(out + i) = o;
}

// ---------------- GEMV: out[n] = dot(x, Wm[n,:]) + bias  (bf16 weight rows) ----
__global__ void gemv_bf16w(const float* __restrict__ x, const unsigned short* __restrict__ Wm,
                           const float* __restrict__ bias, float* __restrict__ out,
                           int N, int K)
{
    int wid = threadIdx.x >> 6;
    int lane = threadIdx.x & 63;
    int n = blockIdx.x * (blockDim.x >> 6) + wid;
    if (n >= N) return;
    const unsigned short* wr = Wm + (size_t)n * K;
    float s = 0.f;
    for (int p = 0; p < K; p += 256) {
        float4 xv = *reinterpret_cast<const float4*>(x + p + lane * 4);
        ushort4 wv = *reinterpret_cast<const ushort4*>(wr + p + lane * 4);
        s = fmaf(xv.x, bf2f(wv.x), s); s = fmaf(xv.y, bf2f(wv.y), s);
        s = fmaf(xv.z, bf2f(wv.z), s); s = fmaf(xv.w, bf2f(wv.w), s);
    }
#pragma unroll
    for (int off = 32; off; off >>= 1) s += __shfl_down(s, off);
    if (lane == 0) out[n] = s + (bias ? bias[n] : 0.f);
}

// ---------------- GRU combine kernels ----------------
__global__ void h1_combine(const float* __restrict__ Gi, const float* __restrict__ gh0,
                           const float* __restrict__ state, float* __restrict__ h1,
                           unsigned short* __restrict__ h1b)
{
    int idx = blockIdx.x * blockDim.x + threadIdx.x;
    int v = idx >> 10, h = idx & (H - 1);
    const float* g = Gi + (size_t)v * H3;
    float r = sigf(g[h] + gh0[h]);
    float z = sigf(g[H + h] + gh0[H + h]);
    float n = tanhf(fmaf(r, gh0[2 * H + h], g[2 * H + h]));
    float v2 = (1.f - z) * n + z * state[h];
    h1[idx] = v2;
    h1b[idx] = f2bf(v2);
}

// step 2 both branches: rows [0,Nr) rel -> h2b; rows [Nr,Ntot) attr -> attr_out
__global__ void step2_both(const int* __restrict__ rel, const int* __restrict__ attr, int Nr,
                           const float* __restrict__ Gi, const float* __restrict__ gh1,
                           const float* __restrict__ h1,
                           unsigned short* __restrict__ h2b, unsigned short* __restrict__ attr_out)
{
    int idx = blockIdx.x * blockDim.x + threadIdx.x;
    int row = idx >> 10, h = idx & (H - 1);
    int t0, t1, orow = row;
    unsigned short* dst;
    if (row < Nr) { t0 = rel[row * 3 + 0]; t1 = rel[row * 3 + 1]; dst = h2b; }
    else { orow = row - Nr; t0 = attr[orow * 2 + 0]; t1 = attr[orow * 2 + 1]; dst = attr_out; }
    const float* g = Gi + (size_t)t1 * H3;
    const float* gh = gh1 + (size_t)t0 * H3;
    float r = sigf(g[h] + gh[h]);
    float z = sigf(g[H + h] + gh[H + h]);
    float n = tanhf(fmaf(r, gh[2 * H + h], g[2 * H + h]));
    float v = (1.f - z) * n + z * h1[(size_t)t0 * H + h];
    dst[(size_t)orow * H + h] = f2bf(v);
}

// rel step 3: bf16 gh2b/h2b -> bf16 clause rows [0, Nr)
__global__ void step3_rel(const int* __restrict__ toks,
                          const float* __restrict__ Gi, const unsigned short* __restrict__ gh2b,
                          const unsigned short* __restrict__ h2b, unsigned short* __restrict__ outb)
{
    int idx = blockIdx.x * blockDim.x + threadIdx.x;
    int row = idx >> 10, h = idx & (H - 1);
    int t2 = toks[row * 3 + 2];
    const float* g = Gi + (size_t)t2 * H3;
    const unsigned short* gh = gh2b + (size_t)row * H3;
    float r = sigf(g[h] + bf2f(gh[h]));
    float z = sigf(g[H + h] + bf2f(gh[H + h]));
    float n = tanhf(fmaf(r, bf2f(gh[2 * H + h]), g[2 * H + h]));
    outb[idx] = f2bf((1.f - z) * n + z * bf2f(h2b[idx]));
}

// ---------------- softmax + eps smoothing ----------------
__global__ void softmax_eps(const float* __restrict__ logits, const float* __restrict__ epsp,
                            float* __restrict__ out, int N)
{
    __shared__ float smax[16], ssum[16];
    int tid = threadIdx.x;
    int nw = blockDim.x >> 6;
    float m = -INFINITY;
    for (int i = tid; i < N; i += blockDim.x) m = fmaxf(m, logits[i]);
#pragma unroll
    for (int off = 32; off; off >>= 1) m = fmaxf(m, __shfl_down(m, off));
    if ((tid & 63) == 0) smax[tid >> 6] = m;
    __syncthreads();
    float M = smax[0];
    for (int i = 1; i < nw; i++) M = fmaxf(M, smax[i]);
    float s = 0.f;
    for (int i = tid; i < N; i += blockDim.x) s += expf(logits[i] - M);
#pragma unroll
    for (int off = 32; off; off >>= 1) s += __shfl_down(s, off);
    if ((tid & 63) == 0) ssum[tid >> 6] = s;
    __syncthreads();
    float S = 0.f;
    for (int i = 0; i < nw; i++) S += ssum[i];
    float e = epsp[0];
    float mul = (1.f - e) / S;
    float add = e / (float)N;
    for (int i = tid; i < N; i += blockDim.x) out[i] = expf(logits[i] - M) * mul + add;
}

extern "C" void kernel_launch(void* const* d_in, const int* in_sizes, int n_in,
                              void* d_out, int out_size, void* d_ws, size_t ws_size,
                              hipStream_t stream)
{
    const float* state       = (const float*)d_in[0];
    const int*   rel_tokens  = (const int*)d_in[1];
    const int*   attr_tokens = (const int*)d_in[2];
    const float* table       = (const float*)d_in[3];
    const float* W_emb       = (const float*)d_in[4];
    const float* b_emb       = (const float*)d_in[5];
    const float* W_ih        = (const float*)d_in[6];
    const float* W_hh        = (const float*)d_in[7];
    const float* b_ih        = (const float*)d_in[8];
    const float* b_hh        = (const float*)d_in[9];
    const float* W1          = (const float*)d_in[10];
    const float* b1          = (const float*)d_in[11];
    const float* W2          = (const float*)d_in[12];
    const float* b2          = (const float*)d_in[13];
    const float* W3          = (const float*)d_in[14];
    // d_in[15] = b3: softmax-invariant, skipped.
    const float* eps         = (const float*)d_in[16];

    const int Nr = in_sizes[1] / 3;   // 4096
    const int Na = in_sizes[2] / 2;   // 4096
    const int Ntot = Nr + Na;         // 8192

    // fp32 workspace
    float* ws     = (float*)d_ws;
    float* Gi     = ws;                               // 256*3072
    float* gh0    = Gi + NVOC * H3;                   // 3072
    float* h1     = gh0 + H3;                         // 256*1024
    float* gh1    = h1 + NVOC * H;                    // 256*3072
    float* emb32  = gh1 + NVOC * H3;                  // 256*1024
    float* logits = emb32 + NVOC * H;                 // Ntot
    // bf16 workspace
    unsigned short* W_hhb   = (unsigned short*)(logits + Ntot);
    unsigned short* W_ihb   = W_hhb + (size_t)H3 * H;
    unsigned short* W1b     = W_ihb + (size_t)H3 * H;
    unsigned short* W2b     = W1b + (size_t)H * H;
    unsigned short* W_embb  = W2b + (size_t)H * H;
    unsigned short* tableb  = W_embb + (size_t)H * H;
    unsigned short* embb    = tableb + (size_t)NVOC * H;
    unsigned short* h1b     = embb + (size_t)NVOC * H;
    unsigned short* h2b     = h1b + (size_t)NVOC * H;       // Nr*1024
    unsigned short* gh2b    = h2b + (size_t)Nr * H;         // Nr*3072
    unsigned short* clauseb = gh2b + (size_t)Nr * H3;       // Ntot*1024
    unsigned short* x1b     = clauseb + (size_t)Ntot * H;   // Ntot*1024

    // W0: weight conversions + bias prefills (independent, at graph head)
    {
        const int total = 2 * H3 * H + 3 * H * H + NVOC * H;
        cvt_all<<<(total / 4 + 255) / 256, 256, 0, stream>>>(
            W_hh, W_ih, W1, W2, W_emb, table,
            W_hhb, W_ihb, W1b, W2b, W_embb, tableb);
        const int pf = NVOC * H + 2 * NVOC * H3 + Ntot;
        prefill<<<(pf + 255) / 256, 256, 0, stream>>>(b_emb, b_ih, b_hh,
                                                      emb32, Gi, gh1, logits, Ntot);
    }

    // K1: emb32 += table @ W_emb^T  (split-K=4, bias prefilled)   [256,1024]
    gemm_bf16<false, 3><<<dim3((H / 128) * (NVOC / 128), 4), 256, 0, stream>>>(
        tableb, W_embb, nullptr, emb32, H, H, H / 128, H / 4, nullptr, nullptr);
    cvt_emb<<<NVOC * H / 4 / 256, 256, 0, stream>>>(emb32, embb);
    // K2: Gi += emb @ W_ih^T  (split-K=4, b_ih prefilled)         [256,3072]
    gemm_bf16<false, 3><<<dim3((H3 / 128) * (NVOC / 128), 4), 256, 0, stream>>>(
        embb, W_ihb, nullptr, Gi, H3, H, H3 / 128, H / 4, nullptr, nullptr);
    // K3: gh0 = state @ W_hh^T + b_hh                             [3072]
    gemv_bf16w<<<H3 / 4, 256, 0, stream>>>(state, W_hhb, b_hh, gh0, H3, H);
    // K4: h1[v] for the 256 distinct tokens
    h1_combine<<<NVOC * H / 256, 256, 0, stream>>>(Gi, gh0, state, h1, h1b);
    // K5: gh1 += h1 @ W_hh^T  (split-K=4, b_hh prefilled)         [256,3072]
    gemm_bf16<false, 3><<<dim3((H3 / 128) * (NVOC / 128), 4), 256, 0, stream>>>(
        h1b, W_hhb, nullptr, gh1, H3, H, H3 / 128, H / 4, nullptr, nullptr);
    // K6: step 2 both branches -> h2b + clauseb[Nr:]
    step2_both<<<Ntot * (H / 256), 256, 0, stream>>>(rel_tokens, attr_tokens, Nr,
                                                     Gi, gh1, h1, h2b,
                                                     clauseb + (size_t)Nr * H);
    // K7: gh2b = h2 @ W_hh^T + b_hh                               [4096,3072]
    gemm_bf16<false, 1><<<dim3((H3 / 128) * (Nr / 128), 1), 256, 0, stream>>>(
        h2b, W_hhb, b_hh, gh2b, H3, H, H3 / 128, H, nullptr, nullptr);
    // K8: rel step 3 -> clauseb rows [0, Nr)
    step3_rel<<<Nr * (H / 256), 256, 0, stream>>>(rel_tokens, Gi, gh2b, h2b, clauseb);
    // K9: x1b = relu(clause @ W1^T + b1)                          [8192,1024]
    gemm_bf16<true, 1><<<dim3((H / 128) * (Ntot / 128), 1), 256, 0, stream>>>(
        clauseb, W1b, b1, x1b, H, H, H / 128, H, nullptr, nullptr);
    // K10+K11 fused: logits[row] += relu(x1 @ W2^T + b2) . W3     [8192]
    gemm_bf16<true, 2><<<dim3((H / 128) * (Ntot / 128), 1), 256, 0, stream>>>(
        x1b, W2b, b2, nullptr, H, H, H / 128, H, W3, logits);
    // K12: softmax + eps smoothing -> d_out
    softmax_eps<<<1, 1024, 0, stream>>>(logits, eps, (float*)d_out, Ntot);
}

// Round 6
// 311.737 us; speedup vs baseline: 3.3133x; 1.0237x over previous
//
#include <hip/hip_runtime.h>
#include <math.h>

#define H 1024
#define H3 3072
#define NVOC 256

typedef __attribute__((ext_vector_type(8))) short bf16x8;
typedef __attribute__((ext_vector_type(4))) float f32x4;

__device__ __forceinline__ float sigf(float x) { return 1.0f / (1.0f + expf(-x)); }

__device__ __forceinline__ unsigned short f2bf(float f) {
    unsigned int u = __float_as_uint(f);
    u = (u + 0x7fffu + ((u >> 16) & 1u)) >> 16;   // RNE
    return (unsigned short)u;
}
__device__ __forceinline__ float bf2f(unsigned short u) {
    return __uint_as_float(((unsigned int)u) << 16);
}

// ============ 256x256 8-phase pipelined bf16 MFMA GEMM (T2+T3+T4+T5) ============
// C[M,N] = A[M,K] @ W[N,K]^T + bias. 512 threads = 8 waves (2M x 4N), BK=64.
// LDS 128 KiB: 2 buffers x (A 32KB [kh][mh][128][32] + B 32KB [kh][256][32]),
// XOR swizzle byte ^= (row&3)<<4 on both stage-source and ds_read address.
// Staging: 4 half-tiles/K-tile {B-k0, A-m03, B-k1, A-m47}, 1 per phase, one-phase
// read-retirement lag; vmcnt(6) at phases 4/8 only (3 half-tiles in flight).
// OUT_MODE: 1 = bf16 C (+bias, opt RELU); 2 = fused dot w3 -> atomicAdd logits.
#define MM256(MH, AV, BV)                                                          \
    __builtin_amdgcn_s_setprio(1);                                                 \
    _Pragma("unroll")                                                              \
    for (int m_ = 0; m_ < 4; ++m_)                                                 \
        _Pragma("unroll")                                                          \
        for (int n_ = 0; n_ < 4; ++n_)                                             \
            acc[(MH) * 4 + m_][n_] = __builtin_amdgcn_mfma_f32_16x16x32_bf16(      \
                AV[m_], BV[n_], acc[(MH) * 4 + m_][n_], 0, 0, 0);                  \
    __builtin_amdgcn_s_setprio(0);

#define RDA256(BUF, KQ, MH)                                                        \
    _Pragma("unroll")                                                              \
    for (int m_ = 0; m_ < 4; ++m_)                                                 \
        a[m_] = *reinterpret_cast<const bf16x8*>(                                  \
            ldsb + (BUF) * 65536 + ((KQ) * 2 + (MH)) * 8192 + m_ * 1024 + aoff);

#define RDB256(BUF, KQ, DST)                                                       \
    _Pragma("unroll")                                                              \
    for (int n_ = 0; n_ < 4; ++n_)                                                 \
        DST[n_] = *reinterpret_cast<const bf16x8*>(                                \
            ldsb + (BUF) * 65536 + (KQ) * 16384 + n_ * 1024 + boff);

#define BAR256() __builtin_amdgcn_s_barrier()

template<bool RELU, int OUT_MODE>
__global__ __launch_bounds__(512, 2)
void gemm256(const unsigned short* __restrict__ A, const unsigned short* __restrict__ W,
             const float* __restrict__ bias, void* __restrict__ C,
             int N, int K, int gx,
             const float* __restrict__ w3, float* __restrict__ logits)
{
    __shared__ unsigned short lds[65536];   // 128 KiB
    char* ldsb = (char*)lds;
    const int tid = threadIdx.x;
    const int wid = tid >> 6, lane = tid & 63;

    // XCD-aware bijective swizzle (grid % 8 == 0 for all launches here)
    const int nwg = gridDim.x;
    const int cpx = nwg >> 3;
    const int bid = blockIdx.x;
    const int swz = (bid & 7) * cpx + (bid >> 3);
    const int bm = (swz / gx) * 256;
    const int bn = (swz % gx) * 256;

    const int g = wid >> 2;              // m-half of the wave
    const int wn = (wid & 3) * 64;       // n-offset of the wave
    const int fr = lane & 15, fq = lane >> 4;

    // frag-read base offsets (XOR swizzle key = fr&3 since other row terms are %4==0)
    const int aoff = (g * 64 + fr) * 64 + ((fq ^ (fr & 3)) * 16);
    const int boff = (wn + fr) * 64 + ((fq ^ (fr & 3)) * 16) + 32768;

    // staging geometry: thread covers LDS bytes tid*16 within each 8KB block;
    // inverse-swizzled source column group:
    const int srow = tid >> 2;                          // 0..127
    const int scol = ((tid & 3) ^ (srow & 3)) * 8;      // source col element offset
    const int arow0 = ((srow >> 6) << 7) + (srow & 63); // A global row for mh=0

    auto stageA = [&](int t, int mh) {   // half {A-m03 | A-m47}: 2 issues (kh=0,1)
        const int buf = t & 1;
        const unsigned short* src = A + (size_t)(bm + arow0 + mh * 64) * K + t * 64 + scol;
#pragma unroll
        for (int kh = 0; kh < 2; ++kh) {
            char* dst = ldsb + buf * 65536 + (kh * 2 + mh) * 8192 + wid * 1024;
            __builtin_amdgcn_global_load_lds(
                (const __attribute__((address_space(1))) void*)(src + kh * 32),
                (__attribute__((address_space(3))) void*)dst, 16, 0, 0);
        }
    };
    auto stageB = [&](int t, int kh) {   // half {B-k0 | B-k1}: 2 issues (row halves)
        const int buf = t & 1;
        const unsigned short* src = W + (size_t)(bn + srow) * K + t * 64 + kh * 32 + scol;
#pragma unroll
        for (int j = 0; j < 2; ++j) {
            char* dst = ldsb + buf * 65536 + 32768 + kh * 16384 + j * 8192 + wid * 1024;
            __builtin_amdgcn_global_load_lds(
                (const __attribute__((address_space(1))) void*)(src + (size_t)j * 128 * K),
                (__attribute__((address_space(3))) void*)dst, 16, 0, 0);
        }
    };

    f32x4 acc[8][4];
#pragma unroll
    for (int i = 0; i < 8; i++)
#pragma unroll
        for (int j = 0; j < 4; j++) acc[i][j] = (f32x4){0.f, 0.f, 0.f, 0.f};
    bf16x8 a[4], b0[4], b1[4];

    const int nt = K >> 6;          // K-tiles of 64 (requires nt even, >= 4)
    const int nIter = nt >> 1;

    // prologue: tile0 complete + tile1 {h0,h1,h2}; 3 half-tiles stay in flight
    stageB(0, 0); stageA(0, 0); stageB(0, 1); stageA(0, 1);
    stageB(1, 0); stageA(1, 0); stageB(1, 1);
    asm volatile("s_waitcnt vmcnt(6)" ::: "memory");
    __builtin_amdgcn_sched_barrier(0);
    BAR256();

    for (int it = 0; it < nIter; ++it) {
        const int t0 = 2 * it;
        const bool full = (it + 1 < nIter);
        // ph1: tile t0 (buf0): A(m0-3,k0), B(*,k0); stage (t0+1)h3
        RDB256(0, 0, b0); RDA256(0, 0, 0);
        stageA(t0 + 1, 1);
        MM256(0, a, b0); BAR256();
        // ph2: A(m0-3,k1), B(*,k1); stage (t0+2)h0
        RDB256(0, 1, b1); RDA256(0, 1, 0);
        if (full) stageB(t0 + 2, 0);
        MM256(0, a, b1); BAR256();
        // ph3: A(m4-7,k0) x retained b0; stage (t0+2)h1
        RDA256(0, 0, 1);
        if (full) stageA(t0 + 2, 0);
        MM256(1, a, b0); BAR256();
        // ph4: A(m4-7,k1) x retained b1; stage (t0+2)h2; tile-boundary vmcnt
        RDA256(0, 1, 1);
        if (full) stageB(t0 + 2, 1);
        MM256(1, a, b1);
        if (full) { asm volatile("s_waitcnt vmcnt(6)" ::: "memory"); }
        else      { asm volatile("s_waitcnt vmcnt(0)" ::: "memory"); }
        __builtin_amdgcn_sched_barrier(0);
        BAR256();
        // ph5: tile t0+1 (buf1): A(m0-3,k0), B(*,k0); stage (t0+2)h3
        RDB256(1, 0, b0); RDA256(1, 0, 0);
        if (full) stageA(t0 + 2, 1);
        MM256(0, a, b0); BAR256();
        // ph6: A(m0-3,k1), B(*,k1); stage (t0+3)h0
        RDB256(1, 1, b1); RDA256(1, 1, 0);
        if (full) stageB(t0 + 3, 0);
        MM256(0, a, b1); BAR256();
        // ph7: A(m4-7,k0); stage (t0+3)h1
        RDA256(1, 0, 1);
        if (full) stageA(t0 + 3, 0);
        MM256(1, a, b0); BAR256();
        // ph8: A(m4-7,k1); stage (t0+3)h2; tile-boundary vmcnt
        RDA256(1, 1, 1);
        if (full) stageB(t0 + 3, 1);
        MM256(1, a, b1);
        if (full) {
            asm volatile("s_waitcnt vmcnt(6)" ::: "memory");
            __builtin_amdgcn_sched_barrier(0);
        }
        BAR256();
    }

    // epilogue; per-wave rows: bm + g*128 + (m>>2)*64 + (m&3)*16 + fq*4 + j
    if (OUT_MODE == 2) {
        float rs[8][4];
#pragma unroll
        for (int m = 0; m < 8; m++)
#pragma unroll
            for (int j = 0; j < 4; j++) rs[m][j] = 0.f;
#pragma unroll
        for (int n = 0; n < 4; n++) {
            const int col = bn + wn + n * 16 + fr;
            const float bv = bias[col];
            const float wv = w3[col];
#pragma unroll
            for (int m = 0; m < 8; m++)
#pragma unroll
                for (int j = 0; j < 4; j++) {
                    float v = acc[m][n][j] + bv;
                    if (RELU) v = fmaxf(v, 0.f);
                    rs[m][j] = fmaf(v, wv, rs[m][j]);
                }
        }
#pragma unroll
        for (int m = 0; m < 8; m++)
#pragma unroll
            for (int j = 0; j < 4; j++) {
                float s = rs[m][j];
                s += __shfl_xor(s, 1); s += __shfl_xor(s, 2);
                s += __shfl_xor(s, 4); s += __shfl_xor(s, 8);
                if (fr == 0) {
                    const int row = bm + g * 128 + (m >> 2) * 64 + (m & 3) * 16 + fq * 4 + j;
                    atomicAdd(logits + row, s);
                }
            }
    } else {
#pragma unroll
        for (int m = 0; m < 8; m++) {
#pragma unroll
            for (int n = 0; n < 4; n++) {
                const int col = bn + wn + n * 16 + fr;
                const float bv = bias[col];
#pragma unroll
                for (int j = 0; j < 4; j++) {
                    const int row = bm + g * 128 + (m >> 2) * 64 + (m & 3) * 16 + fq * 4 + j;
                    float v = acc[m][n][j] + bv;
                    if (RELU) v = fmaxf(v, 0.f);
                    ((unsigned short*)C)[(size_t)row * N + col] = f2bf(v);
                }
            }
        }
    }
}

// ============ 128x128 ring GEMM (small/split-K matrices, from R5) ============
template<bool RELU, int OUT_MODE>   // 3 = fp32 atomicAdd (split-K)
__global__ __launch_bounds__(256)
void gemm_bf16(const unsigned short* __restrict__ A, const unsigned short* __restrict__ W,
               const float* __restrict__ bias, void* __restrict__ C,
               int N, int K, int gx, int Kc,
               const float* __restrict__ w3, float* __restrict__ logits)
{
    __shared__ unsigned short As[4][128 * 32];
    __shared__ unsigned short Ws[4][128 * 32];
    const int tid = threadIdx.x;
    const int wid = tid >> 6, lane = tid & 63;

    const int nwg = gridDim.x;
    const int cpx = nwg >> 3;
    const int bid = blockIdx.x;
    const int swz = (bid & 7) * cpx + (bid >> 3);
    const int bm = (swz / gx) * 128;
    const int bn = (swz % gx) * 128;
    const int k_base = blockIdx.y * Kc;
    const int nt = Kc >> 5;

    const int wm = (wid >> 1) * 64, wn = (wid & 1) * 64;
    const int fr = lane & 15;
    const int fq = lane >> 4;
    const int perm = fq ^ (fr & 3);

    f32x4 acc[4][4];
#pragma unroll
    for (int i = 0; i < 4; i++)
#pragma unroll
        for (int j = 0; j < 4; j++) acc[i][j] = (f32x4){0.f, 0.f, 0.f, 0.f};

    const int srow = tid >> 2;
    const int schunk = (tid & 3) ^ (srow & 3);
    const unsigned short* aS = A + (size_t)(bm + srow) * K + k_base + schunk * 8;
    const unsigned short* wS = W + (size_t)(bn + srow) * K + k_base + schunk * 8;
    const size_t rstep = (size_t)64 * K;

    auto stage = [&](int b, int t) {
        const unsigned short* a0 = aS + t * 32;
        const unsigned short* w0 = wS + t * 32;
        __builtin_amdgcn_global_load_lds(
            (const __attribute__((address_space(1))) void*)a0,
            (__attribute__((address_space(3))) void*)(&As[b][wid * 512]), 16, 0, 0);
        __builtin_amdgcn_global_load_lds(
            (const __attribute__((address_space(1))) void*)(a0 + rstep),
            (__attribute__((address_space(3))) void*)(&As[b][2048 + wid * 512]), 16, 0, 0);
        __builtin_amdgcn_global_load_lds(
            (const __attribute__((address_space(1))) void*)w0,
            (__attribute__((address_space(3))) void*)(&Ws[b][wid * 512]), 16, 0, 0);
        __builtin_amdgcn_global_load_lds(
            (const __attribute__((address_space(1))) void*)(w0 + rstep),
            (__attribute__((address_space(3))) void*)(&Ws[b][2048 + wid * 512]), 16, 0, 0);
    };

    stage(0, 0);
    if (nt > 1) stage(1, 1);
    if (nt > 2) stage(2, 2);

    for (int t = 0; t < nt; ++t) {
        if (t + 2 < nt)      asm volatile("s_waitcnt vmcnt(8)" ::: "memory");
        else if (t + 1 < nt) asm volatile("s_waitcnt vmcnt(4)" ::: "memory");
        else                 asm volatile("s_waitcnt vmcnt(0)" ::: "memory");
        __builtin_amdgcn_s_barrier();
        __builtin_amdgcn_sched_barrier(0);
        if (t + 3 < nt) stage((t + 3) & 3, t + 3);

        const unsigned short* as = &As[t & 3][0];
        const unsigned short* ws = &Ws[t & 3][0];
        bf16x8 a[4], b[4];
#pragma unroll
        for (int m = 0; m < 4; m++)
            a[m] = *reinterpret_cast<const bf16x8*>(as + (wm + m * 16 + fr) * 32 + perm * 8);
#pragma unroll
        for (int n = 0; n < 4; n++)
            b[n] = *reinterpret_cast<const bf16x8*>(ws + (wn + n * 16 + fr) * 32 + perm * 8);
        __builtin_amdgcn_s_setprio(1);
#pragma unroll
        for (int m = 0; m < 4; m++)
#pragma unroll
            for (int n = 0; n < 4; n++)
                acc[m][n] = __builtin_amdgcn_mfma_f32_16x16x32_bf16(a[m], b[n], acc[m][n], 0, 0, 0);
        __builtin_amdgcn_s_setprio(0);
    }

    if (OUT_MODE == 3) {
        float* Cf = (float*)C;
#pragma unroll
        for (int m = 0; m < 4; m++)
#pragma unroll
            for (int n = 0; n < 4; n++) {
                const int col = bn + wn + n * 16 + fr;
#pragma unroll
                for (int j = 0; j < 4; j++) {
                    const int row = bm + wm + m * 16 + fq * 4 + j;
                    atomicAdd(Cf + (size_t)row * N + col, acc[m][n][j]);
                }
            }
    } else {
#pragma unroll
        for (int m = 0; m < 4; m++) {
#pragma unroll
            for (int n = 0; n < 4; n++) {
                const int col = bn + wn + n * 16 + fr;
                const float bv = bias[col];
#pragma unroll
                for (int j = 0; j < 4; j++) {
                    const int row = bm + wm + m * 16 + fq * 4 + j;
                    float v = acc[m][n][j] + bv;
                    if (RELU) v = fmaxf(v, 0.f);
                    if (OUT_MODE == 1)
                        ((unsigned short*)C)[(size_t)row * N + col] = f2bf(v);
                    else
                        ((float*)C)[(size_t)row * N + col] = v;
                }
            }
        }
    }
}

// ---------------- fused fp32 -> bf16 conversion of all weights ----------------
__global__ void cvt_all(const float* __restrict__ W_hh, const float* __restrict__ W_ih,
                        const float* __restrict__ W1, const float* __restrict__ W2,
                        const float* __restrict__ W_emb, const float* __restrict__ table,
                        unsigned short* __restrict__ W_hhb, unsigned short* __restrict__ W_ihb,
                        unsigned short* __restrict__ W1b, unsigned short* __restrict__ W2b,
                        unsigned short* __restrict__ W_embb, unsigned short* __restrict__ tableb)
{
    const int C1 = H3 * H, C2 = H * H, C3 = NVOC * H;
    int off = (blockIdx.x * blockDim.x + threadIdx.x) * 4;
    const float* src; unsigned short* dst;
    if (off < C1)               { src = W_hh;  dst = W_hhb; }
    else if ((off -= C1) < C1)  { src = W_ih;  dst = W_ihb; }
    else if ((off -= C1) < C2)  { src = W1;    dst = W1b; }
    else if ((off -= C2) < C2)  { src = W2;    dst = W2b; }
    else if ((off -= C2) < C2)  { src = W_emb; dst = W_embb; }
    else if ((off -= C2) < C3)  { src = table; dst = tableb; }
    else return;
    float4 v = *reinterpret_cast<const float4*>(src + off);
    ushort4 o;
    o.x = f2bf(v.x); o.y = f2bf(v.y); o.z = f2bf(v.z); o.w = f2bf(v.w);
    *reinterpret_cast<ushort4*>(dst + off) = o;
}

// ---------------- bias prefill for split-K accumulators + logits zero ----------
__global__ void prefill(const float* __restrict__ b_emb, const float* __restrict__ b_ih,
                        const float* __restrict__ b_hh,
                        float* __restrict__ emb32, float* __restrict__ Gi,
                        float* __restrict__ gh1, float* __restrict__ logits, int Ntot)
{
    const int E = NVOC * H, G = NVOC * H3;
    int i = blockIdx.x * blockDim.x + threadIdx.x;
    if (i < E)                { emb32[i] = b_emb[i & (H - 1)]; return; }
    if ((i -= E) < G)         { Gi[i] = b_ih[i % H3]; return; }
    if ((i -= G) < G)         { gh1[i] = b_hh[i % H3]; return; }
    if ((i -= G) < Ntot)      logits[i] = 0.f;
}

// ---------------- fp32 -> bf16 (emb) ----------------
__global__ void cvt_emb(const float* __restrict__ in, unsigned short* __restrict__ out)
{
    int i = (blockIdx.x * blockDim.x + threadIdx.x) * 4;
    float4 v = *reinterpret_cast<const float4*>(in + i);
    ushort4 o;
    o.x = f2bf(v.x); o.y = f2bf(v.y); o.z = f2bf(v.z); o.w = f2bf(v.w);
    *reinterpret_cast<ushort4*>(out + i) = o;
}

// ---------------- GEMV: out[n] = dot(x, Wm[n,:]) + bias  (bf16 weight rows) ----
__global__ void gemv_bf16w(const float* __restrict__ x, const unsigned short* __restrict__ Wm,
                           const float* __restrict__ bias, float* __restrict__ out,
                           int N, int K)
{
    int wid = threadIdx.x >> 6;
    int lane = threadIdx.x & 63;
    int n = blockIdx.x * (blockDim.x >> 6) + wid;
    if (n >= N) return;
    const unsigned short* wr = Wm + (size_t)n * K;
    float s = 0.f;
    for (int p = 0; p < K; p += 256) {
        float4 xv = *reinterpret_cast<const float4*>(x + p + lane * 4);
        ushort4 wv = *reinterpret_cast<const ushort4*>(wr + p + lane * 4);
        s = fmaf(xv.x, bf2f(wv.x), s); s = fmaf(xv.y, bf2f(wv.y), s);
        s = fmaf(xv.z, bf2f(wv.z), s); s = fmaf(xv.w, bf2f(wv.w), s);
    }
#pragma unroll
    for (int off = 32; off; off >>= 1) s += __shfl_down(s, off);
    if (lane == 0) out[n] = s + (bias ? bias[n] : 0.f);
}

// ---------------- GRU combine kernels ----------------
__global__ void h1_combine(const float* __restrict__ Gi, const float* __restrict__ gh0,
                           const float* __restrict__ state, float* __restrict__ h1,
                           unsigned short* __restrict__ h1b)
{
    int idx = blockIdx.x * blockDim.x + threadIdx.x;
    int v = idx >> 10, h = idx & (H - 1);
    const float* g = Gi + (size_t)v * H3;
    float r = sigf(g[h] + gh0[h]);
    float z = sigf(g[H + h] + gh0[H + h]);
    float n = tanhf(fmaf(r, gh0[2 * H + h], g[2 * H + h]));
    float v2 = (1.f - z) * n + z * state[h];
    h1[idx] = v2;
    h1b[idx] = f2bf(v2);
}

// step 2 both branches: rows [0,Nr) rel -> h2b; rows [Nr,Ntot) attr -> attr_out
__global__ void step2_both(const int* __restrict__ rel, const int* __restrict__ attr, int Nr,
                           const float* __restrict__ Gi, const float* __restrict__ gh1,
                           const float* __restrict__ h1,
                           unsigned short* __restrict__ h2b, unsigned short* __restrict__ attr_out)
{
    int idx = blockIdx.x * blockDim.x + threadIdx.x;
    int row = idx >> 10, h = idx & (H - 1);
    int t0, t1, orow = row;
    unsigned short* dst;
    if (row < Nr) { t0 = rel[row * 3 + 0]; t1 = rel[row * 3 + 1]; dst = h2b; }
    else { orow = row - Nr; t0 = attr[orow * 2 + 0]; t1 = attr[orow * 2 + 1]; dst = attr_out; }
    const float* g = Gi + (size_t)t1 * H3;
    const float* gh = gh1 + (size_t)t0 * H3;
    float r = sigf(g[h] + gh[h]);
    float z = sigf(g[H + h] + gh[H + h]);
    float n = tanhf(fmaf(r, gh[2 * H + h], g[2 * H + h]));
    float v = (1.f - z) * n + z * h1[(size_t)t0 * H + h];
    dst[(size_t)orow * H + h] = f2bf(v);
}

// rel step 3: bf16 gh2b/h2b -> bf16 clause rows [0, Nr)
__global__ void step3_rel(const int* __restrict__ toks,
                          const float* __restrict__ Gi, const unsigned short* __restrict__ gh2b,
                          const unsigned short* __restrict__ h2b, unsigned short* __restrict__ outb)
{
    int idx = blockIdx.x * blockDim.x + threadIdx.x;
    int row = idx >> 10, h = idx & (H - 1);
    int t2 = toks[row * 3 + 2];
    const float* g = Gi + (size_t)t2 * H3;
    const unsigned short* gh = gh2b + (size_t)row * H3;
    float r = sigf(g[h] + bf2f(gh[h]));
    float z = sigf(g[H + h] + bf2f(gh[H + h]));
    float n = tanhf(fmaf(r, bf2f(gh[2 * H + h]), g[2 * H + h]));
    outb[idx] = f2bf((1.f - z) * n + z * bf2f(h2b[idx]));
}

// ---------------- softmax + eps smoothing ----------------
__global__ void softmax_eps(const float* __restrict__ logits, const float* __restrict__ epsp,
                            float* __restrict__ out, int N)
{
    __shared__ float smax[16], ssum[16];
    int tid = threadIdx.x;
    int nw = blockDim.x >> 6;
    float m = -INFINITY;
    for (int i = tid; i < N; i += blockDim.x) m = fmaxf(m, logits[i]);
#pragma unroll
    for (int off = 32; off; off >>= 1) m = fmaxf(m, __shfl_down(m, off));
    if ((tid & 63) == 0) smax[tid >> 6] = m;
    __syncthreads();
    float M = smax[0];
    for (int i = 1; i < nw; i++) M = fmaxf(M, smax[i]);
    float s = 0.f;
    for (int i = tid; i < N; i += blockDim.x) s += expf(logits[i] - M);
#pragma unroll
    for (int off = 32; off; off >>= 1) s += __shfl_down(s, off);
    if ((tid & 63) == 0) ssum[tid >> 6] = s;
    __syncthreads();
    float S = 0.f;
    for (int i = 0; i < nw; i++) S += ssum[i];
    float e = epsp[0];
    float mul = (1.f - e) / S;
    float add = e / (float)N;
    for (int i = tid; i < N; i += blockDim.x) out[i] = expf(logits[i] - M) * mul + add;
}

extern "C" void kernel_launch(void* const* d_in, const int* in_sizes, int n_in,
                              void* d_out, int out_size, void* d_ws, size_t ws_size,
                              hipStream_t stream)
{
    const float* state       = (const float*)d_in[0];
    const int*   rel_tokens  = (const int*)d_in[1];
    const int*   attr_tokens = (const int*)d_in[2];
    const float* table       = (const float*)d_in[3];
    const float* W_emb       = (const float*)d_in[4];
    const float* b_emb       = (const float*)d_in[5];
    const float* W_ih        = (const float*)d_in[6];
    const float* W_hh        = (const float*)d_in[7];
    const float* b_ih        = (const float*)d_in[8];
    const float* b_hh        = (const float*)d_in[9];
    const float* W1          = (const float*)d_in[10];
    const float* b1          = (const float*)d_in[11];
    const float* W2          = (const float*)d_in[12];
    const float* b2          = (const float*)d_in[13];
    const float* W3          = (const float*)d_in[14];
    // d_in[15] = b3: softmax-invariant, skipped.
    const float* eps         = (const float*)d_in[16];

    const int Nr = in_sizes[1] / 3;   // 4096
    const int Na = in_sizes[2] / 2;   // 4096
    const int Ntot = Nr + Na;         // 8192

    // fp32 workspace
    float* ws     = (float*)d_ws;
    float* Gi     = ws;                               // 256*3072
    float* gh0    = Gi + NVOC * H3;                   // 3072
    float* h1     = gh0 + H3;                         // 256*1024
    float* gh1    = h1 + NVOC * H;                    // 256*3072
    float* emb32  = gh1 + NVOC * H3;                  // 256*1024
    float* logits = emb32 + NVOC * H;                 // Ntot
    // bf16 workspace
    unsigned short* W_hhb   = (unsigned short*)(logits + Ntot);
    unsigned short* W_ihb   = W_hhb + (size_t)H3 * H;
    unsigned short* W1b     = W_ihb + (size_t)H3 * H;
    unsigned short* W2b     = W1b + (size_t)H * H;
    unsigned short* W_embb  = W2b + (size_t)H * H;
    unsigned short* tableb  = W_embb + (size_t)H * H;
    unsigned short* embb    = tableb + (size_t)NVOC * H;
    unsigned short* h1b     = embb + (size_t)NVOC * H;
    unsigned short* h2b     = h1b + (size_t)NVOC * H;       // Nr*1024
    unsigned short* gh2b    = h2b + (size_t)Nr * H;         // Nr*3072
    unsigned short* clauseb = gh2b + (size_t)Nr * H3;       // Ntot*1024
    unsigned short* x1b     = clauseb + (size_t)Ntot * H;   // Ntot*1024

    // W0: weight conversions + bias prefills
    {
        const int total = 2 * H3 * H + 3 * H * H + NVOC * H;
        cvt_all<<<(total / 4 + 255) / 256, 256, 0, stream>>>(
            W_hh, W_ih, W1, W2, W_emb, table,
            W_hhb, W_ihb, W1b, W2b, W_embb, tableb);
        const int pf = NVOC * H + 2 * NVOC * H3 + Ntot;
        prefill<<<(pf + 255) / 256, 256, 0, stream>>>(b_emb, b_ih, b_hh,
                                                      emb32, Gi, gh1, logits, Ntot);
    }

    // K1: emb32 += table @ W_emb^T  (split-K=4, bias prefilled)   [256,1024]
    gemm_bf16<false, 3><<<dim3((H / 128) * (NVOC / 128), 4), 256, 0, stream>>>(
        tableb, W_embb, nullptr, emb32, H, H, H / 128, H / 4, nullptr, nullptr);
    cvt_emb<<<NVOC * H / 4 / 256, 256, 0, stream>>>(emb32, embb);
    // K2: Gi += emb @ W_ih^T  (split-K=4, b_ih prefilled)         [256,3072]
    gemm_bf16<false, 3><<<dim3((H3 / 128) * (NVOC / 128), 4), 256, 0, stream>>>(
        embb, W_ihb, nullptr, Gi, H3, H, H3 / 128, H / 4, nullptr, nullptr);
    // K3: gh0 = state @ W_hh^T + b_hh                             [3072]
    gemv_bf16w<<<H3 / 4, 256, 0, stream>>>(state, W_hhb, b_hh, gh0, H3, H);
    // K4: h1[v] for the 256 distinct tokens
    h1_combine<<<NVOC * H / 256, 256, 0, stream>>>(Gi, gh0, state, h1, h1b);
    // K5: gh1 += h1 @ W_hh^T  (split-K=4, b_hh prefilled)         [256,3072]
    gemm_bf16<false, 3><<<dim3((H3 / 128) * (NVOC / 128), 4), 256, 0, stream>>>(
        h1b, W_hhb, nullptr, gh1, H3, H, H3 / 128, H / 4, nullptr, nullptr);
    // K6: step 2 both branches -> h2b + clauseb[Nr:]
    step2_both<<<Ntot * (H / 256), 256, 0, stream>>>(rel_tokens, attr_tokens, Nr,
                                                     Gi, gh1, h1, h2b,
                                                     clauseb + (size_t)Nr * H);
    // K7: gh2b = h2 @ W_hh^T + b_hh     [4096,3072]  256^2 8-phase
    gemm256<false, 1><<<(Nr / 256) * (H3 / 256), 512, 0, stream>>>(
        h2b, W_hhb, b_hh, gh2b, H3, H, H3 / 256, nullptr, nullptr);
    // K8: rel step 3 -> clauseb rows [0, Nr)
    step3_rel<<<Nr * (H / 256), 256, 0, stream>>>(rel_tokens, Gi, gh2b, h2b, clauseb);
    // K9: x1b = relu(clause @ W1^T + b1)  [8192,1024]  256^2 8-phase
    gemm256<true, 1><<<(Ntot / 256) * (H / 256), 512, 0, stream>>>(
        clauseb, W1b, b1, x1b, H, H, H / 256, nullptr, nullptr);
    // K10+K11 fused: logits += relu(x1 @ W2^T + b2) . W3  [8192]  256^2 8-phase
    gemm256<true, 2><<<(Ntot / 256) * (H / 256), 512, 0, stream>>>(
        x1b, W2b, b2, nullptr, H, H, H / 256, W3, logits);
    // K12: softmax + eps smoothing -> d_out
    softmax_eps<<<1, 1024, 0, stream>>>(logits, eps, (float*)d_out, Ntot);
}

// Round 7
// 303.503 us; speedup vs baseline: 3.4032x; 1.0271x over previous
//
#include <hip/hip_runtime.h>
#include <math.h>

#define H 1024
#define H3 3072
#define NVOC 256

typedef __attribute__((ext_vector_type(8))) short bf16x8;
typedef __attribute__((ext_vector_type(4))) float f32x4;

__device__ __forceinline__ float sigf(float x) { return 1.0f / (1.0f + expf(-x)); }

__device__ __forceinline__ unsigned short f2bf(float f) {
    unsigned int u = __float_as_uint(f);
    u = (u + 0x7fffu + ((u >> 16) & 1u)) >> 16;   // RNE
    return (unsigned short)u;
}
__device__ __forceinline__ float bf2f(unsigned short u) {
    return __uint_as_float(((unsigned int)u) << 16);
}

// ============ 256x256 8-phase bf16 MFMA GEMM, 128B-row LDS + 3-bit XOR swizzle ===
// C[M,N] = A[M,K] @ W[N,K]^T + bias. 512 thr = 8 waves (2M x 4N), BK=64.
// LDS 128 KiB: 2 bufs x (A[256][64] 32KB + B[256][64] 32KB). Swizzle: 16B-chunk
// slot = chunk ^ (row&7) on BOTH stage-source and ds_read (residual 2-way = free).
// Staging: 8x 8KB units/tile (1 gload_lds/lane each). Per tile (4 phases):
//   ph1 RD(A-mh0,k0 + B,k0) stage(t+1,u1) | ph2 RD(..k1) stage(t+1,u3)
//   ph3 RD(A-mh1,k0)  stage(t+2,{u0,u2,u4}) | ph4 RD(A-mh1,k1) stage(t+2,{u5,u6,u7})
//   vmcnt(6) once per tile at ph4 (retires exactly tile t+1). All hazards verified.
// OUT_MODE: 1 = bf16 C (+bias, opt RELU); 2 = fused dot w3 -> atomicAdd logits.
#define MM256(MH, AV, BV)                                                          \
    __builtin_amdgcn_s_setprio(1);                                                 \
    _Pragma("unroll")                                                              \
    for (int m_ = 0; m_ < 4; ++m_)                                                 \
        _Pragma("unroll")                                                          \
        for (int n_ = 0; n_ < 4; ++n_)                                             \
            acc[(MH) * 4 + m_][n_] = __builtin_amdgcn_mfma_f32_16x16x32_bf16(      \
                AV[m_], BV[n_], acc[(MH) * 4 + m_][n_], 0, 0, 0);                  \
    __builtin_amdgcn_s_setprio(0);

#define RDA256(BUF, MH, KQ)                                                        \
    _Pragma("unroll")                                                              \
    for (int m_ = 0; m_ < 4; ++m_)                                                 \
        a[m_] = *reinterpret_cast<const bf16x8*>(                                  \
            ldsb + (BUF) * 65536 + (g * 128 + (MH) * 64 + m_ * 16 + fr) * 128 +    \
            (((KQ) * 4 + fq) ^ (fr & 7)) * 16);

#define RDB256(BUF, KQ, DST)                                                       \
    _Pragma("unroll")                                                              \
    for (int n_ = 0; n_ < 4; ++n_)                                                 \
        DST[n_] = *reinterpret_cast<const bf16x8*>(                                \
            ldsb + (BUF) * 65536 + 32768 + (wn + n_ * 16 + fr) * 128 +             \
            (((KQ) * 4 + fq) ^ (fr & 7)) * 16);

#define BAR256() __builtin_amdgcn_s_barrier()

template<bool RELU, int OUT_MODE>
__global__ __launch_bounds__(512, 2)
void gemm256(const unsigned short* __restrict__ A, const unsigned short* __restrict__ W,
             const float* __restrict__ bias, void* __restrict__ C,
             int N, int K, int gx,
             const float* __restrict__ w3, float* __restrict__ logits)
{
    __shared__ unsigned short lds[65536];   // 128 KiB
    char* ldsb = (char*)lds;
    const int tid = threadIdx.x;
    const int wid = tid >> 6, lane = tid & 63;

    // XCD-aware bijective swizzle (grid % 8 == 0 for all launches here)
    const int nwg = gridDim.x;
    const int cpx = nwg >> 3;
    const int bid = blockIdx.x;
    const int swz = (bid & 7) * cpx + (bid >> 3);
    const int bm = (swz / gx) * 256;
    const int bn = (swz % gx) * 256;

    const int g = wid >> 2;              // m-half of the wave (0..1)
    const int wn = (wid & 3) * 64;       // n-offset of the wave
    const int fr = lane & 15, fq = lane >> 4;

    // staging: unit u = rows [u*64, u*64+64) of A (u<4) or B (u-4); thread covers
    // 16B: local row = tid>>3, slot = tid&7 holds source chunk (tid&7)^(row&7).
    const int sr = tid >> 3;                      // 0..63 local row
    const int sc = ((tid & 7) ^ (sr & 7)) * 8;    // inverse-swizzled source col elem
    auto stage_unit = [&](int t, int u) {
        const unsigned short* src = (u < 4)
            ? A + (size_t)(bm + u * 64 + sr) * K + t * 64 + sc
            : W + (size_t)(bn + (u - 4) * 64 + sr) * K + t * 64 + sc;
        char* dst = ldsb + (t & 1) * 65536 + u * 8192 + tid * 16;
        __builtin_amdgcn_global_load_lds(
            (const __attribute__((address_space(1))) void*)src,
            (__attribute__((address_space(3))) void*)dst, 16, 0, 0);
    };

    f32x4 acc[8][4];
#pragma unroll
    for (int i = 0; i < 8; i++)
#pragma unroll
        for (int j = 0; j < 4; j++) acc[i][j] = (f32x4){0.f, 0.f, 0.f, 0.f};
    bf16x8 a[4], b0[4], b1[4];

    const int nt = K >> 6;          // K-tiles of 64 (nt >= 3, even; here K=1024)

    // prologue: tile0 all 8 units + tile1 {u0,u2,u4,u5,u6,u7} -> vmcnt(6) = tile0 done
#pragma unroll
    for (int u = 0; u < 8; ++u) stage_unit(0, u);
    stage_unit(1, 0); stage_unit(1, 2); stage_unit(1, 4);
    stage_unit(1, 5); stage_unit(1, 6); stage_unit(1, 7);
    asm volatile("s_waitcnt vmcnt(6)" ::: "memory");
    __builtin_amdgcn_sched_barrier(0);
    BAR256();

    for (int t = 0; t < nt; ++t) {
        const int buf = t & 1;
        // ph1: A(mh0,k0) + B(k0); stage (t+1,u1) into other buf
        RDB256(buf, 0, b0); RDA256(buf, 0, 0);
        if (t + 1 < nt) stage_unit(t + 1, 1);
        MM256(0, a, b0); BAR256();
        // ph2: A(mh0,k1) + B(k1); stage (t+1,u3)
        RDB256(buf, 1, b1); RDA256(buf, 0, 1);
        if (t + 1 < nt) stage_unit(t + 1, 3);
        MM256(0, a, b1); BAR256();
        // ph3: A(mh1,k0) x retained b0; stage (t+2,{u0,u2,u4}) into current buf
        RDA256(buf, 1, 0);
        if (t + 2 < nt) { stage_unit(t + 2, 0); stage_unit(t + 2, 2); stage_unit(t + 2, 4); }
        MM256(1, a, b0); BAR256();
        // ph4: A(mh1,k1) x retained b1; stage (t+2,{u5,u6,u7}); tile-boundary vmcnt
        RDA256(buf, 1, 1);
        if (t + 2 < nt) { stage_unit(t + 2, 5); stage_unit(t + 2, 6); stage_unit(t + 2, 7); }
        MM256(1, a, b1);
        if (t + 2 < nt) {
            asm volatile("s_waitcnt vmcnt(6)" ::: "memory");
            __builtin_amdgcn_sched_barrier(0);
        } else if (t + 1 < nt) {
            asm volatile("s_waitcnt vmcnt(0)" ::: "memory");
            __builtin_amdgcn_sched_barrier(0);
        }
        BAR256();
    }

    // epilogue; rows: bm + g*128 + (m>>2)*64 + (m&3)*16 + fq*4 + j
    if (OUT_MODE == 2) {
        float rs[8][4];
#pragma unroll
        for (int m = 0; m < 8; m++)
#pragma unroll
            for (int j = 0; j < 4; j++) rs[m][j] = 0.f;
#pragma unroll
        for (int n = 0; n < 4; n++) {
            const int col = bn + wn + n * 16 + fr;
            const float bv = bias[col];
            const float wv = w3[col];
#pragma unroll
            for (int m = 0; m < 8; m++)
#pragma unroll
                for (int j = 0; j < 4; j++) {
                    float v = acc[m][n][j] + bv;
                    if (RELU) v = fmaxf(v, 0.f);
                    rs[m][j] = fmaf(v, wv, rs[m][j]);
                }
        }
#pragma unroll
        for (int m = 0; m < 8; m++)
#pragma unroll
            for (int j = 0; j < 4; j++) {
                float s = rs[m][j];
                s += __shfl_xor(s, 1); s += __shfl_xor(s, 2);
                s += __shfl_xor(s, 4); s += __shfl_xor(s, 8);
                if (fr == 0) {
                    const int row = bm + g * 128 + (m >> 2) * 64 + (m & 3) * 16 + fq * 4 + j;
                    atomicAdd(logits + row, s);
                }
            }
    } else {
#pragma unroll
        for (int m = 0; m < 8; m++) {
#pragma unroll
            for (int n = 0; n < 4; n++) {
                const int col = bn + wn + n * 16 + fr;
                const float bv = bias[col];
#pragma unroll
                for (int j = 0; j < 4; j++) {
                    const int row = bm + g * 128 + (m >> 2) * 64 + (m & 3) * 16 + fq * 4 + j;
                    float v = acc[m][n][j] + bv;
                    if (RELU) v = fmaxf(v, 0.f);
                    ((unsigned short*)C)[(size_t)row * N + col] = f2bf(v);
                }
            }
        }
    }
}

// ============ 128x128 ring GEMM (small/split-K matrices, unchanged) ============
template<bool RELU, int OUT_MODE>   // 3 = fp32 atomicAdd (split-K)
__global__ __launch_bounds__(256)
void gemm_bf16(const unsigned short* __restrict__ A, const unsigned short* __restrict__ W,
               const float* __restrict__ bias, void* __restrict__ C,
               int N, int K, int gx, int Kc,
               const float* __restrict__ w3, float* __restrict__ logits)
{
    __shared__ unsigned short As[4][128 * 32];
    __shared__ unsigned short Ws[4][128 * 32];
    const int tid = threadIdx.x;
    const int wid = tid >> 6, lane = tid & 63;

    const int nwg = gridDim.x;
    const int cpx = nwg >> 3;
    const int bid = blockIdx.x;
    const int swz = (bid & 7) * cpx + (bid >> 3);
    const int bm = (swz / gx) * 128;
    const int bn = (swz % gx) * 128;
    const int k_base = blockIdx.y * Kc;
    const int nt = Kc >> 5;

    const int wm = (wid >> 1) * 64, wn = (wid & 1) * 64;
    const int fr = lane & 15;
    const int fq = lane >> 4;
    const int perm = fq ^ (fr & 3);

    f32x4 acc[4][4];
#pragma unroll
    for (int i = 0; i < 4; i++)
#pragma unroll
        for (int j = 0; j < 4; j++) acc[i][j] = (f32x4){0.f, 0.f, 0.f, 0.f};

    const int srow = tid >> 2;
    const int schunk = (tid & 3) ^ (srow & 3);
    const unsigned short* aS = A + (size_t)(bm + srow) * K + k_base + schunk * 8;
    const unsigned short* wS = W + (size_t)(bn + srow) * K + k_base + schunk * 8;
    const size_t rstep = (size_t)64 * K;

    auto stage = [&](int b, int t) {
        const unsigned short* a0 = aS + t * 32;
        const unsigned short* w0 = wS + t * 32;
        __builtin_amdgcn_global_load_lds(
            (const __attribute__((address_space(1))) void*)a0,
            (__attribute__((address_space(3))) void*)(&As[b][wid * 512]), 16, 0, 0);
        __builtin_amdgcn_global_load_lds(
            (const __attribute__((address_space(1))) void*)(a0 + rstep),
            (__attribute__((address_space(3))) void*)(&As[b][2048 + wid * 512]), 16, 0, 0);
        __builtin_amdgcn_global_load_lds(
            (const __attribute__((address_space(1))) void*)w0,
            (__attribute__((address_space(3))) void*)(&Ws[b][wid * 512]), 16, 0, 0);
        __builtin_amdgcn_global_load_lds(
            (const __attribute__((address_space(1))) void*)(w0 + rstep),
            (__attribute__((address_space(3))) void*)(&Ws[b][2048 + wid * 512]), 16, 0, 0);
    };

    stage(0, 0);
    if (nt > 1) stage(1, 1);
    if (nt > 2) stage(2, 2);

    for (int t = 0; t < nt; ++t) {
        if (t + 2 < nt)      asm volatile("s_waitcnt vmcnt(8)" ::: "memory");
        else if (t + 1 < nt) asm volatile("s_waitcnt vmcnt(4)" ::: "memory");
        else                 asm volatile("s_waitcnt vmcnt(0)" ::: "memory");
        __builtin_amdgcn_s_barrier();
        __builtin_amdgcn_sched_barrier(0);
        if (t + 3 < nt) stage((t + 3) & 3, t + 3);

        const unsigned short* as = &As[t & 3][0];
        const unsigned short* ws = &Ws[t & 3][0];
        bf16x8 a[4], b[4];
#pragma unroll
        for (int m = 0; m < 4; m++)
            a[m] = *reinterpret_cast<const bf16x8*>(as + (wm + m * 16 + fr) * 32 + perm * 8);
#pragma unroll
        for (int n = 0; n < 4; n++)
            b[n] = *reinterpret_cast<const bf16x8*>(ws + (wn + n * 16 + fr) * 32 + perm * 8);
        __builtin_amdgcn_s_setprio(1);
#pragma unroll
        for (int m = 0; m < 4; m++)
#pragma unroll
            for (int n = 0; n < 4; n++)
                acc[m][n] = __builtin_amdgcn_mfma_f32_16x16x32_bf16(a[m], b[n], acc[m][n], 0, 0, 0);
        __builtin_amdgcn_s_setprio(0);
    }

    if (OUT_MODE == 3) {
        float* Cf = (float*)C;
#pragma unroll
        for (int m = 0; m < 4; m++)
#pragma unroll
            for (int n = 0; n < 4; n++) {
                const int col = bn + wn + n * 16 + fr;
#pragma unroll
                for (int j = 0; j < 4; j++) {
                    const int row = bm + wm + m * 16 + fq * 4 + j;
                    atomicAdd(Cf + (size_t)row * N + col, acc[m][n][j]);
                }
            }
    } else {
#pragma unroll
        for (int m = 0; m < 4; m++) {
#pragma unroll
            for (int n = 0; n < 4; n++) {
                const int col = bn + wn + n * 16 + fr;
                const float bv = bias[col];
#pragma unroll
                for (int j = 0; j < 4; j++) {
                    const int row = bm + wm + m * 16 + fq * 4 + j;
                    float v = acc[m][n][j] + bv;
                    if (RELU) v = fmaxf(v, 0.f);
                    if (OUT_MODE == 1)
                        ((unsigned short*)C)[(size_t)row * N + col] = f2bf(v);
                    else
                        ((float*)C)[(size_t)row * N + col] = v;
                }
            }
        }
    }
}

// ========= prep: all weight cvt + gh0 gemv (fused with W_hh read) + prefill =====
// grid layout (blocks of 256 thr, 1024 elems each):
//   [0,3072)       W_hh rows: cvt + gh0[row] = dot(state,row)+b_hh[row]
//   [3072,6144)    W_ih cvt
//   [6144,7168)    W1 cvt | [7168,8192) W2 cvt | [8192,9216) W_emb cvt
//   [9216,9472)    table cvt
//   [9472,9728)    emb32 = b_emb bcast | [9728,10496) Gi = b_ih bcast
//   [10496,11264)  gh1 = b_hh bcast    | [11264,11272) logits = 0
__global__ __launch_bounds__(256)
void prep(const float* __restrict__ W_hh, const float* __restrict__ W_ih,
          const float* __restrict__ W1, const float* __restrict__ W2,
          const float* __restrict__ W_emb, const float* __restrict__ table,
          const float* __restrict__ state, const float* __restrict__ b_emb,
          const float* __restrict__ b_ih, const float* __restrict__ b_hh,
          unsigned short* __restrict__ W_hhb, unsigned short* __restrict__ W_ihb,
          unsigned short* __restrict__ W1b, unsigned short* __restrict__ W2b,
          unsigned short* __restrict__ W_embb, unsigned short* __restrict__ tableb,
          float* __restrict__ gh0, float* __restrict__ emb32, float* __restrict__ Gi,
          float* __restrict__ gh1, float* __restrict__ logits)
{
    int b = blockIdx.x;
    const int t = threadIdx.x;
    if (b < 3072) {   // W_hh row b: convert + fused gemv
        float4 w = *reinterpret_cast<const float4*>(W_hh + (size_t)b * H + t * 4);
        ushort4 o; o.x = f2bf(w.x); o.y = f2bf(w.y); o.z = f2bf(w.z); o.w = f2bf(w.w);
        *reinterpret_cast<ushort4*>(W_hhb + (size_t)b * H + t * 4) = o;
        float4 sv = *reinterpret_cast<const float4*>(state + t * 4);
        float s = w.x * sv.x + w.y * sv.y + w.z * sv.z + w.w * sv.w;
#pragma unroll
        for (int off = 32; off; off >>= 1) s += __shfl_down(s, off);
        __shared__ float ps[4];
        if ((t & 63) == 0) ps[t >> 6] = s;
        __syncthreads();
        if (t == 0) gh0[b] = ps[0] + ps[1] + ps[2] + ps[3] + b_hh[b];
        return;
    }
    b -= 3072;
    const float* src = nullptr; unsigned short* dst = nullptr;
    if (b < 3072)      { src = W_ih;  dst = W_ihb; }
    else if ((b -= 3072) < 1024) { src = W1; dst = W1b; }
    else if ((b -= 1024) < 1024) { src = W2; dst = W2b; }
    else if ((b -= 1024) < 1024) { src = W_emb; dst = W_embb; }
    else if ((b -= 1024) < 256)  { src = table; dst = tableb; }
    else {
        b -= 256;
        if (b < 256) {        // emb32 = b_emb broadcast
            int i = b * 1024 + t * 4;
            *reinterpret_cast<float4*>(emb32 + i) =
                *reinterpret_cast<const float4*>(b_emb + (i & (H - 1)));
        } else if ((b -= 256) < 768) {   // Gi = b_ih broadcast
            int i = b * 1024 + t * 4;
            *reinterpret_cast<float4*>(Gi + i) =
                *reinterpret_cast<const float4*>(b_ih + i % H3);
        } else if ((b -= 768) < 768) {   // gh1 = b_hh broadcast
            int i = b * 1024 + t * 4;
            *reinterpret_cast<float4*>(gh1 + i) =
                *reinterpret_cast<const float4*>(b_hh + i % H3);
        } else {                          // logits = 0
            b -= 768;
            int i = b * 1024 + t * 4;
            *reinterpret_cast<float4*>(logits + i) = (float4){0.f, 0.f, 0.f, 0.f};
        }
        return;
    }
    const int off = b * 1024 + t * 4;
    float4 v = *reinterpret_cast<const float4*>(src + off);
    ushort4 o; o.x = f2bf(v.x); o.y = f2bf(v.y); o.z = f2bf(v.z); o.w = f2bf(v.w);
    *reinterpret_cast<ushort4*>(dst + off) = o;
}

// ---------------- fp32 -> bf16 (emb) ----------------
__global__ void cvt_emb(const float* __restrict__ in, unsigned short* __restrict__ out)
{
    int i = (blockIdx.x * blockDim.x + threadIdx.x) * 4;
    float4 v = *reinterpret_cast<const float4*>(in + i);
    ushort4 o;
    o.x = f2bf(v.x); o.y = f2bf(v.y); o.z = f2bf(v.z); o.w = f2bf(v.w);
    *reinterpret_cast<ushort4*>(out + i) = o;
}

// ---------------- GRU combine kernels ----------------
__global__ void h1_combine(const float* __restrict__ Gi, const float* __restrict__ gh0,
                           const float* __restrict__ state, float* __restrict__ h1,
                           unsigned short* __restrict__ h1b)
{
    int idx = blockIdx.x * blockDim.x + threadIdx.x;
    int v = idx >> 10, h = idx & (H - 1);
    const float* g = Gi + (size_t)v * H3;
    float r = sigf(g[h] + gh0[h]);
    float z = sigf(g[H + h] + gh0[H + h]);
    float n = tanhf(fmaf(r, gh0[2 * H + h], g[2 * H + h]));
    float v2 = (1.f - z) * n + z * state[h];
    h1[idx] = v2;
    h1b[idx] = f2bf(v2);
}

// step 2 both branches: rows [0,Nr) rel -> h2b; rows [Nr,Ntot) attr -> attr_out
__global__ void step2_both(const int* __restrict__ rel, const int* __restrict__ attr, int Nr,
                           const float* __restrict__ Gi, const float* __restrict__ gh1,
                           const float* __restrict__ h1,
                           unsigned short* __restrict__ h2b, unsigned short* __restrict__ attr_out)
{
    int idx = blockIdx.x * blockDim.x + threadIdx.x;
    int row = idx >> 10, h = idx & (H - 1);
    int t0, t1, orow = row;
    unsigned short* dst;
    if (row < Nr) { t0 = rel[row * 3 + 0]; t1 = rel[row * 3 + 1]; dst = h2b; }
    else { orow = row - Nr; t0 = attr[orow * 2 + 0]; t1 = attr[orow * 2 + 1]; dst = attr_out; }
    const float* g = Gi + (size_t)t1 * H3;
    const float* gh = gh1 + (size_t)t0 * H3;
    float r = sigf(g[h] + gh[h]);
    float z = sigf(g[H + h] + gh[H + h]);
    float n = tanhf(fmaf(r, gh[2 * H + h], g[2 * H + h]));
    float v = (1.f - z) * n + z * h1[(size_t)t0 * H + h];
    dst[(size_t)orow * H + h] = f2bf(v);
}

// rel step 3: bf16 gh2b/h2b -> bf16 clause rows [0, Nr)
__global__ void step3_rel(const int* __restrict__ toks,
                          const float* __restrict__ Gi, const unsigned short* __restrict__ gh2b,
                          const unsigned short* __restrict__ h2b, unsigned short* __restrict__ outb)
{
    int idx = blockIdx.x * blockDim.x + threadIdx.x;
    int row = idx >> 10, h = idx & (H - 1);
    int t2 = toks[row * 3 + 2];
    const float* g = Gi + (size_t)t2 * H3;
    const unsigned short* gh = gh2b + (size_t)row * H3;
    float r = sigf(g[h] + bf2f(gh[h]));
    float z = sigf(g[H + h] + bf2f(gh[H + h]));
    float n = tanhf(fmaf(r, bf2f(gh[2 * H + h]), g[2 * H + h]));
    outb[idx] = f2bf((1.f - z) * n + z * bf2f(h2b[idx]));
}

// ---------------- softmax + eps smoothing ----------------
__global__ void softmax_eps(const float* __restrict__ logits, const float* __restrict__ epsp,
                            float* __restrict__ out, int N)
{
    __shared__ float smax[16], ssum[16];
    int tid = threadIdx.x;
    int nw = blockDim.x >> 6;
    float m = -INFINITY;
    for (int i = tid; i < N; i += blockDim.x) m = fmaxf(m, logits[i]);
#pragma unroll
    for (int off = 32; off; off >>= 1) m = fmaxf(m, __shfl_down(m, off));
    if ((tid & 63) == 0) smax[tid >> 6] = m;
    __syncthreads();
    float M = smax[0];
    for (int i = 1; i < nw; i++) M = fmaxf(M, smax[i]);
    float s = 0.f;
    for (int i = tid; i < N; i += blockDim.x) s += expf(logits[i] - M);
#pragma unroll
    for (int off = 32; off; off >>= 1) s += __shfl_down(s, off);
    if ((tid & 63) == 0) ssum[tid >> 6] = s;
    __syncthreads();
    float S = 0.f;
    for (int i = 0; i < nw; i++) S += ssum[i];
    float e = epsp[0];
    float mul = (1.f - e) / S;
    float add = e / (float)N;
    for (int i = tid; i < N; i += blockDim.x) out[i] = expf(logits[i] - M) * mul + add;
}

extern "C" void kernel_launch(void* const* d_in, const int* in_sizes, int n_in,
                              void* d_out, int out_size, void* d_ws, size_t ws_size,
                              hipStream_t stream)
{
    const float* state       = (const float*)d_in[0];
    const int*   rel_tokens  = (const int*)d_in[1];
    const int*   attr_tokens = (const int*)d_in[2];
    const float* table       = (const float*)d_in[3];
    const float* W_emb       = (const float*)d_in[4];
    const float* b_emb       = (const float*)d_in[5];
    const float* W_ih        = (const float*)d_in[6];
    const float* W_hh        = (const float*)d_in[7];
    const float* b_ih        = (const float*)d_in[8];
    const float* b_hh        = (const float*)d_in[9];
    const float* W1          = (const float*)d_in[10];
    const float* b1          = (const float*)d_in[11];
    const float* W2          = (const float*)d_in[12];
    const float* b2          = (const float*)d_in[13];
    const float* W3          = (const float*)d_in[14];
    // d_in[15] = b3: softmax-invariant, skipped.
    const float* eps         = (const float*)d_in[16];

    const int Nr = in_sizes[1] / 3;   // 4096
    const int Na = in_sizes[2] / 2;   // 4096
    const int Ntot = Nr + Na;         // 8192

    // fp32 workspace
    float* ws     = (float*)d_ws;
    float* Gi     = ws;                               // 256*3072
    float* gh0    = Gi + NVOC * H3;                   // 3072
    float* h1     = gh0 + H3;                         // 256*1024
    float* gh1    = h1 + NVOC * H;                    // 256*3072
    float* emb32  = gh1 + NVOC * H3;                  // 256*1024
    float* logits = emb32 + NVOC * H;                 // Ntot
    // bf16 workspace
    unsigned short* W_hhb   = (unsigned short*)(logits + Ntot);
    unsigned short* W_ihb   = W_hhb + (size_t)H3 * H;
    unsigned short* W1b     = W_ihb + (size_t)H3 * H;
    unsigned short* W2b     = W1b + (size_t)H * H;
    unsigned short* W_embb  = W2b + (size_t)H * H;
    unsigned short* tableb  = W_embb + (size_t)H * H;
    unsigned short* embb    = tableb + (size_t)NVOC * H;
    unsigned short* h1b     = embb + (size_t)NVOC * H;
    unsigned short* h2b     = h1b + (size_t)NVOC * H;       // Nr*1024
    unsigned short* gh2b    = h2b + (size_t)Nr * H;         // Nr*3072
    unsigned short* clauseb = gh2b + (size_t)Nr * H3;       // Ntot*1024
    unsigned short* x1b     = clauseb + (size_t)Ntot * H;   // Ntot*1024

    // P0: all weight cvt + gh0 gemv + bias prefills + logits zero, one launch
    prep<<<11272, 256, 0, stream>>>(W_hh, W_ih, W1, W2, W_emb, table, state,
                                    b_emb, b_ih, b_hh,
                                    W_hhb, W_ihb, W1b, W2b, W_embb, tableb,
                                    gh0, emb32, Gi, gh1, logits);

    // K1: emb32 += table @ W_emb^T  (split-K=4, bias prefilled)   [256,1024]
    gemm_bf16<false, 3><<<dim3((H / 128) * (NVOC / 128), 4), 256, 0, stream>>>(
        tableb, W_embb, nullptr, emb32, H, H, H / 128, H / 4, nullptr, nullptr);
    cvt_emb<<<NVOC * H / 4 / 256, 256, 0, stream>>>(emb32, embb);
    // K2: Gi += emb @ W_ih^T  (split-K=4, b_ih prefilled)         [256,3072]
    gemm_bf16<false, 3><<<dim3((H3 / 128) * (NVOC / 128), 4), 256, 0, stream>>>(
        embb, W_ihb, nullptr, Gi, H3, H, H3 / 128, H / 4, nullptr, nullptr);
    // K4: h1[v] for the 256 distinct tokens
    h1_combine<<<NVOC * H / 256, 256, 0, stream>>>(Gi, gh0, state, h1, h1b);
    // K5: gh1 += h1 @ W_hh^T  (split-K=4, b_hh prefilled)         [256,3072]
    gemm_bf16<false, 3><<<dim3((H3 / 128) * (NVOC / 128), 4), 256, 0, stream>>>(
        h1b, W_hhb, nullptr, gh1, H3, H, H3 / 128, H / 4, nullptr, nullptr);
    // K6: step 2 both branches -> h2b + clauseb[Nr:]
    step2_both<<<Ntot * (H / 256), 256, 0, stream>>>(rel_tokens, attr_tokens, Nr,
                                                     Gi, gh1, h1, h2b,
                                                     clauseb + (size_t)Nr * H);
    // K7: gh2b = h2 @ W_hh^T + b_hh     [4096,3072]  256^2 8-phase (new swizzle)
    gemm256<false, 1><<<(Nr / 256) * (H3 / 256), 512, 0, stream>>>(
        h2b, W_hhb, b_hh, gh2b, H3, H, H3 / 256, nullptr, nullptr);
    // K8: rel step 3 -> clauseb rows [0, Nr)
    step3_rel<<<Nr * (H / 256), 256, 0, stream>>>(rel_tokens, Gi, gh2b, h2b, clauseb);
    // K9: x1b = relu(clause @ W1^T + b1)  [8192,1024]
    gemm256<true, 1><<<(Ntot / 256) * (H / 256), 512, 0, stream>>>(
        clauseb, W1b, b1, x1b, H, H, H / 256, nullptr, nullptr);
    // K10+K11 fused: logits += relu(x1 @ W2^T + b2) . W3  [8192]
    gemm256<true, 2><<<(Ntot / 256) * (H / 256), 512, 0, stream>>>(
        x1b, W2b, b2, nullptr, H, H, H / 256, W3, logits);
    // K12: softmax + eps smoothing -> d_out
    softmax_eps<<<1, 1024, 0, stream>>>(logits, eps, (float*)d_out, Ntot);
}

// Round 8
// 282.046 us; speedup vs baseline: 3.6621x; 1.0761x over previous
//
#include <hip/hip_runtime.h>
#include <math.h>

#define H 1024
#define H3 3072
#define NVOC 256

typedef __attribute__((ext_vector_type(8))) short bf16x8;
typedef __attribute__((ext_vector_type(4))) float f32x4;

__device__ __forceinline__ float sigf(float x) { return 1.0f / (1.0f + expf(-x)); }

__device__ __forceinline__ unsigned short f2bf(float f) {
    unsigned int u = __float_as_uint(f);
    u = (u + 0x7fffu + ((u >> 16) & 1u)) >> 16;   // RNE
    return (unsigned short)u;
}
__device__ __forceinline__ float bf2f(unsigned short u) {
    return __uint_as_float(((unsigned int)u) << 16);
}

// ============ 256x256 8-phase bf16 MFMA GEMM (proven R7 kernel, used for K7) ====
#define MM256(MH, AV, BV)                                                          \
    __builtin_amdgcn_s_setprio(1);                                                 \
    _Pragma("unroll")                                                              \
    for (int m_ = 0; m_ < 4; ++m_)                                                 \
        _Pragma("unroll")                                                          \
        for (int n_ = 0; n_ < 4; ++n_)                                             \
            acc[(MH) * 4 + m_][n_] = __builtin_amdgcn_mfma_f32_16x16x32_bf16(      \
                AV[m_], BV[n_], acc[(MH) * 4 + m_][n_], 0, 0, 0);                  \
    __builtin_amdgcn_s_setprio(0);

#define RDA256(BUF, MH, KQ)                                                        \
    _Pragma("unroll")                                                              \
    for (int m_ = 0; m_ < 4; ++m_)                                                 \
        a[m_] = *reinterpret_cast<const bf16x8*>(                                  \
            ldsb + (BUF) * 65536 + (g * 128 + (MH) * 64 + m_ * 16 + fr) * 128 +    \
            (((KQ) * 4 + fq) ^ (fr & 7)) * 16);

#define RDB256(BUF, KQ, DST)                                                       \
    _Pragma("unroll")                                                              \
    for (int n_ = 0; n_ < 4; ++n_)                                                 \
        DST[n_] = *reinterpret_cast<const bf16x8*>(                                \
            ldsb + (BUF) * 65536 + 32768 + (wn + n_ * 16 + fr) * 128 +             \
            (((KQ) * 4 + fq) ^ (fr & 7)) * 16);

#define BAR256() __builtin_amdgcn_s_barrier()

template<bool RELU, int OUT_MODE>
__global__ __launch_bounds__(512, 2)
void gemm256(const unsigned short* __restrict__ A, const unsigned short* __restrict__ W,
             const float* __restrict__ bias, void* __restrict__ C,
             int N, int K, int gx,
             const float* __restrict__ w3, float* __restrict__ logits)
{
    __shared__ unsigned short lds[65536];   // 128 KiB
    char* ldsb = (char*)lds;
    const int tid = threadIdx.x;
    const int wid = tid >> 6, lane = tid & 63;

    const int nwg = gridDim.x;
    const int cpx = nwg >> 3;
    const int bid = blockIdx.x;
    const int swz = (bid & 7) * cpx + (bid >> 3);
    const int bm = (swz / gx) * 256;
    const int bn = (swz % gx) * 256;

    const int g = wid >> 2;
    const int wn = (wid & 3) * 64;
    const int fr = lane & 15, fq = lane >> 4;

    const int sr = tid >> 3;
    const int sc = ((tid & 7) ^ (sr & 7)) * 8;
    auto stage_unit = [&](int t, int u) {
        const unsigned short* src = (u < 4)
            ? A + (size_t)(bm + u * 64 + sr) * K + t * 64 + sc
            : W + (size_t)(bn + (u - 4) * 64 + sr) * K + t * 64 + sc;
        char* dst = ldsb + (t & 1) * 65536 + u * 8192 + tid * 16;
        __builtin_amdgcn_global_load_lds(
            (const __attribute__((address_space(1))) void*)src,
            (__attribute__((address_space(3))) void*)dst, 16, 0, 0);
    };

    f32x4 acc[8][4];
#pragma unroll
    for (int i = 0; i < 8; i++)
#pragma unroll
        for (int j = 0; j < 4; j++) acc[i][j] = (f32x4){0.f, 0.f, 0.f, 0.f};
    bf16x8 a[4], b0[4], b1[4];

    const int nt = K >> 6;

#pragma unroll
    for (int u = 0; u < 8; ++u) stage_unit(0, u);
    stage_unit(1, 0); stage_unit(1, 2); stage_unit(1, 4);
    stage_unit(1, 5); stage_unit(1, 6); stage_unit(1, 7);
    asm volatile("s_waitcnt vmcnt(6)" ::: "memory");
    __builtin_amdgcn_sched_barrier(0);
    BAR256();

    for (int t = 0; t < nt; ++t) {
        const int buf = t & 1;
        RDB256(buf, 0, b0); RDA256(buf, 0, 0);
        if (t + 1 < nt) stage_unit(t + 1, 1);
        MM256(0, a, b0); BAR256();
        RDB256(buf, 1, b1); RDA256(buf, 0, 1);
        if (t + 1 < nt) stage_unit(t + 1, 3);
        MM256(0, a, b1); BAR256();
        RDA256(buf, 1, 0);
        if (t + 2 < nt) { stage_unit(t + 2, 0); stage_unit(t + 2, 2); stage_unit(t + 2, 4); }
        MM256(1, a, b0); BAR256();
        RDA256(buf, 1, 1);
        if (t + 2 < nt) { stage_unit(t + 2, 5); stage_unit(t + 2, 6); stage_unit(t + 2, 7); }
        MM256(1, a, b1);
        if (t + 2 < nt) {
            asm volatile("s_waitcnt vmcnt(6)" ::: "memory");
            __builtin_amdgcn_sched_barrier(0);
        } else if (t + 1 < nt) {
            asm volatile("s_waitcnt vmcnt(0)" ::: "memory");
            __builtin_amdgcn_sched_barrier(0);
        }
        BAR256();
    }

    if (OUT_MODE == 2) {
        float rs[8][4];
#pragma unroll
        for (int m = 0; m < 8; m++)
#pragma unroll
            for (int j = 0; j < 4; j++) rs[m][j] = 0.f;
#pragma unroll
        for (int n = 0; n < 4; n++) {
            const int col = bn + wn + n * 16 + fr;
            const float bv = bias[col];
            const float wv = w3[col];
#pragma unroll
            for (int m = 0; m < 8; m++)
#pragma unroll
                for (int j = 0; j < 4; j++) {
                    float v = acc[m][n][j] + bv;
                    if (RELU) v = fmaxf(v, 0.f);
                    rs[m][j] = fmaf(v, wv, rs[m][j]);
                }
        }
#pragma unroll
        for (int m = 0; m < 8; m++)
#pragma unroll
            for (int j = 0; j < 4; j++) {
                float s = rs[m][j];
                s += __shfl_xor(s, 1); s += __shfl_xor(s, 2);
                s += __shfl_xor(s, 4); s += __shfl_xor(s, 8);
                if (fr == 0) {
                    const int row = bm + g * 128 + (m >> 2) * 64 + (m & 3) * 16 + fq * 4 + j;
                    atomicAdd(logits + row, s);
                }
            }
    } else {
#pragma unroll
        for (int m = 0; m < 8; m++) {
#pragma unroll
            for (int n = 0; n < 4; n++) {
                const int col = bn + wn + n * 16 + fr;
                const float bv = bias[col];
#pragma unroll
                for (int j = 0; j < 4; j++) {
                    const int row = bm + g * 128 + (m >> 2) * 64 + (m & 3) * 16 + fq * 4 + j;
                    float v = acc[m][n][j] + bv;
                    if (RELU) v = fmaxf(v, 0.f);
                    ((unsigned short*)C)[(size_t)row * N + col] = f2bf(v);
                }
            }
        }
    }
}

// ============ NEW: 128x256-tile, 3-buffer, 2-phase counted-vmcnt GEMM ==========
// For M-tall/N-narrow shapes (K9/K10: grid 256 = full chip at 1 block/CU).
// LDS 144 KiB = 3 bufs x (A[128][64] 16KB + B[256][64] 32KB). 6 stage units of
// 8KB per K-tile. Stage tile t+2 during tile t: buf (t+2)%3's last reader was
// tile t-1 (retired at its end-of-tile barrier) -> any phase may stage.
// vmcnt(6) once per tile = exactly tile t+1 arrived, t+2's 6 units in flight.
template<bool RELU, int OUT_MODE>   // 1: bf16 C (+bias,RELU); 2: fused w3 dot
__global__ __launch_bounds__(512, 2)
void gemm_n(const unsigned short* __restrict__ A, const unsigned short* __restrict__ W,
            const float* __restrict__ bias, void* __restrict__ C,
            int N, int K, int gx,
            const float* __restrict__ w3, float* __restrict__ logits)
{
    __shared__ unsigned short lds[73728];   // 144 KiB
    char* ldsb = (char*)lds;
    const int tid = threadIdx.x;
    const int wid = tid >> 6, lane = tid & 63;

    const int nwg = gridDim.x;
    const int cpx = nwg >> 3;
    const int bid = blockIdx.x;
    const int swz = (bid & 7) * cpx + (bid >> 3);
    const int bm = (swz / gx) * 128;
    const int bn = (swz % gx) * 256;

    const int g = wid >> 2;              // m-half (64 rows)
    const int wn = (wid & 3) * 64;
    const int fr = lane & 15, fq = lane >> 4;

    const int sr = tid >> 3;                      // 0..63 local row
    const int sc = ((tid & 7) ^ (sr & 7)) * 8;    // inverse-swizzled source col
    auto stage_unit = [&](int t, int u) {         // u: 0-1 A rows, 2-5 B rows
        const unsigned short* src = (u < 2)
            ? A + (size_t)(bm + u * 64 + sr) * K + t * 64 + sc
            : W + (size_t)(bn + (u - 2) * 64 + sr) * K + t * 64 + sc;
        char* dst = ldsb + (t % 3) * 49152 + u * 8192 + tid * 16;
        __builtin_amdgcn_global_load_lds(
            (const __attribute__((address_space(1))) void*)src,
            (__attribute__((address_space(3))) void*)dst, 16, 0, 0);
    };

    f32x4 acc[4][4];
#pragma unroll
    for (int i = 0; i < 4; i++)
#pragma unroll
        for (int j = 0; j < 4; j++) acc[i][j] = (f32x4){0.f, 0.f, 0.f, 0.f};
    bf16x8 a[4], b[4];

    const int nt = K >> 6;   // >= 2

    // prologue: tiles 0 and 1 fully staged; wait tile 0 (6 of 12 outstanding)
#pragma unroll
    for (int u = 0; u < 6; ++u) stage_unit(0, u);
#pragma unroll
    for (int u = 0; u < 6; ++u) stage_unit(1, u);
    asm volatile("s_waitcnt vmcnt(6)" ::: "memory");
    __builtin_amdgcn_sched_barrier(0);
    __builtin_amdgcn_s_barrier();

    for (int t = 0; t < nt; ++t) {
        const int buf = (t % 3) * 49152;
        // ph1 (k-quarter pair 0): reads + stage 3 units of t+2 + 16 MFMA
#pragma unroll
        for (int n_ = 0; n_ < 4; ++n_)
            b[n_] = *reinterpret_cast<const bf16x8*>(
                ldsb + buf + 16384 + (wn + n_ * 16 + fr) * 128 + ((fq) ^ (fr & 7)) * 16);
#pragma unroll
        for (int m_ = 0; m_ < 4; ++m_)
            a[m_] = *reinterpret_cast<const bf16x8*>(
                ldsb + buf + (g * 64 + m_ * 16 + fr) * 128 + ((fq) ^ (fr & 7)) * 16);
        if (t + 2 < nt) { stage_unit(t + 2, 0); stage_unit(t + 2, 1); stage_unit(t + 2, 2); }
        __builtin_amdgcn_s_setprio(1);
#pragma unroll
        for (int m_ = 0; m_ < 4; ++m_)
#pragma unroll
            for (int n_ = 0; n_ < 4; ++n_)
                acc[m_][n_] = __builtin_amdgcn_mfma_f32_16x16x32_bf16(a[m_], b[n_], acc[m_][n_], 0, 0, 0);
        __builtin_amdgcn_s_setprio(0);
        __builtin_amdgcn_s_barrier();
        // ph2 (k-quarter pair 1)
#pragma unroll
        for (int n_ = 0; n_ < 4; ++n_)
            b[n_] = *reinterpret_cast<const bf16x8*>(
                ldsb + buf + 16384 + (wn + n_ * 16 + fr) * 128 + ((4 + fq) ^ (fr & 7)) * 16);
#pragma unroll
        for (int m_ = 0; m_ < 4; ++m_)
            a[m_] = *reinterpret_cast<const bf16x8*>(
                ldsb + buf + (g * 64 + m_ * 16 + fr) * 128 + ((4 + fq) ^ (fr & 7)) * 16);
        if (t + 2 < nt) { stage_unit(t + 2, 3); stage_unit(t + 2, 4); stage_unit(t + 2, 5); }
        __builtin_amdgcn_s_setprio(1);
#pragma unroll
        for (int m_ = 0; m_ < 4; ++m_)
#pragma unroll
            for (int n_ = 0; n_ < 4; ++n_)
                acc[m_][n_] = __builtin_amdgcn_mfma_f32_16x16x32_bf16(a[m_], b[n_], acc[m_][n_], 0, 0, 0);
        __builtin_amdgcn_s_setprio(0);
        if (t + 2 < nt) {
            asm volatile("s_waitcnt vmcnt(6)" ::: "memory");
            __builtin_amdgcn_sched_barrier(0);
        } else if (t + 1 < nt) {
            asm volatile("s_waitcnt vmcnt(0)" ::: "memory");
            __builtin_amdgcn_sched_barrier(0);
        }
        __builtin_amdgcn_s_barrier();
    }

    // epilogue; rows: bm + g*64 + m*16 + fq*4 + j; cols: bn + wn + n*16 + fr
    if (OUT_MODE == 2) {
        float rs[4][4];
#pragma unroll
        for (int m = 0; m < 4; m++)
#pragma unroll
            for (int j = 0; j < 4; j++) rs[m][j] = 0.f;
#pragma unroll
        for (int n = 0; n < 4; n++) {
            const int col = bn + wn + n * 16 + fr;
            const float bv = bias[col];
            const float wv = w3[col];
#pragma unroll
            for (int m = 0; m < 4; m++)
#pragma unroll
                for (int j = 0; j < 4; j++) {
                    float v = acc[m][n][j] + bv;
                    if (RELU) v = fmaxf(v, 0.f);
                    rs[m][j] = fmaf(v, wv, rs[m][j]);
                }
        }
#pragma unroll
        for (int m = 0; m < 4; m++)
#pragma unroll
            for (int j = 0; j < 4; j++) {
                float s = rs[m][j];
                s += __shfl_xor(s, 1); s += __shfl_xor(s, 2);
                s += __shfl_xor(s, 4); s += __shfl_xor(s, 8);
                if (fr == 0) atomicAdd(logits + bm + g * 64 + m * 16 + fq * 4 + j, s);
            }
    } else {
#pragma unroll
        for (int m = 0; m < 4; m++) {
#pragma unroll
            for (int n = 0; n < 4; n++) {
                const int col = bn + wn + n * 16 + fr;
                const float bv = bias[col];
#pragma unroll
                for (int j = 0; j < 4; j++) {
                    const int row = bm + g * 64 + m * 16 + fq * 4 + j;
                    float v = acc[m][n][j] + bv;
                    if (RELU) v = fmaxf(v, 0.f);
                    ((unsigned short*)C)[(size_t)row * N + col] = f2bf(v);
                }
            }
        }
    }
}

// ============ 128x128 ring GEMM (small/split-K matrices, unchanged) ============
template<bool RELU, int OUT_MODE>   // 3 = fp32 atomicAdd (split-K)
__global__ __launch_bounds__(256)
void gemm_bf16(const unsigned short* __restrict__ A, const unsigned short* __restrict__ W,
               const float* __restrict__ bias, void* __restrict__ C,
               int N, int K, int gx, int Kc,
               const float* __restrict__ w3, float* __restrict__ logits)
{
    __shared__ unsigned short As[4][128 * 32];
    __shared__ unsigned short Ws[4][128 * 32];
    const int tid = threadIdx.x;
    const int wid = tid >> 6, lane = tid & 63;

    const int nwg = gridDim.x;
    const int cpx = nwg >> 3;
    const int bid = blockIdx.x;
    const int swz = (bid & 7) * cpx + (bid >> 3);
    const int bm = (swz / gx) * 128;
    const int bn = (swz % gx) * 128;
    const int k_base = blockIdx.y * Kc;
    const int nt = Kc >> 5;

    const int wm = (wid >> 1) * 64, wn = (wid & 1) * 64;
    const int fr = lane & 15;
    const int fq = lane >> 4;
    const int perm = fq ^ (fr & 3);

    f32x4 acc[4][4];
#pragma unroll
    for (int i = 0; i < 4; i++)
#pragma unroll
        for (int j = 0; j < 4; j++) acc[i][j] = (f32x4){0.f, 0.f, 0.f, 0.f};

    const int srow = tid >> 2;
    const int schunk = (tid & 3) ^ (srow & 3);
    const unsigned short* aS = A + (size_t)(bm + srow) * K + k_base + schunk * 8;
    const unsigned short* wS = W + (size_t)(bn + srow) * K + k_base + schunk * 8;
    const size_t rstep = (size_t)64 * K;

    auto stage = [&](int b, int t) {
        const unsigned short* a0 = aS + t * 32;
        const unsigned short* w0 = wS + t * 32;
        __builtin_amdgcn_global_load_lds(
            (const __attribute__((address_space(1))) void*)a0,
            (__attribute__((address_space(3))) void*)(&As[b][wid * 512]), 16, 0, 0);
        __builtin_amdgcn_global_load_lds(
            (const __attribute__((address_space(1))) void*)(a0 + rstep),
            (__attribute__((address_space(3))) void*)(&As[b][2048 + wid * 512]), 16, 0, 0);
        __builtin_amdgcn_global_load_lds(
            (const __attribute__((address_space(1))) void*)w0,
            (__attribute__((address_space(3))) void*)(&Ws[b][wid * 512]), 16, 0, 0);
        __builtin_amdgcn_global_load_lds(
            (const __attribute__((address_space(1))) void*)(w0 + rstep),
            (__attribute__((address_space(3))) void*)(&Ws[b][2048 + wid * 512]), 16, 0, 0);
    };

    stage(0, 0);
    if (nt > 1) stage(1, 1);
    if (nt > 2) stage(2, 2);

    for (int t = 0; t < nt; ++t) {
        if (t + 2 < nt)      asm volatile("s_waitcnt vmcnt(8)" ::: "memory");
        else if (t + 1 < nt) asm volatile("s_waitcnt vmcnt(4)" ::: "memory");
        else                 asm volatile("s_waitcnt vmcnt(0)" ::: "memory");
        __builtin_amdgcn_s_barrier();
        __builtin_amdgcn_sched_barrier(0);
        if (t + 3 < nt) stage((t + 3) & 3, t + 3);

        const unsigned short* as = &As[t & 3][0];
        const unsigned short* ws = &Ws[t & 3][0];
        bf16x8 a[4], b[4];
#pragma unroll
        for (int m = 0; m < 4; m++)
            a[m] = *reinterpret_cast<const bf16x8*>(as + (wm + m * 16 + fr) * 32 + perm * 8);
#pragma unroll
        for (int n = 0; n < 4; n++)
            b[n] = *reinterpret_cast<const bf16x8*>(ws + (wn + n * 16 + fr) * 32 + perm * 8);
        __builtin_amdgcn_s_setprio(1);
#pragma unroll
        for (int m = 0; m < 4; m++)
#pragma unroll
            for (int n = 0; n < 4; n++)
                acc[m][n] = __builtin_amdgcn_mfma_f32_16x16x32_bf16(a[m], b[n], acc[m][n], 0, 0, 0);
        __builtin_amdgcn_s_setprio(0);
    }

    if (OUT_MODE == 3) {
        float* Cf = (float*)C;
#pragma unroll
        for (int m = 0; m < 4; m++)
#pragma unroll
            for (int n = 0; n < 4; n++) {
                const int col = bn + wn + n * 16 + fr;
#pragma unroll
                for (int j = 0; j < 4; j++) {
                    const int row = bm + wm + m * 16 + fq * 4 + j;
                    atomicAdd(Cf + (size_t)row * N + col, acc[m][n][j]);
                }
            }
    } else {
#pragma unroll
        for (int m = 0; m < 4; m++) {
#pragma unroll
            for (int n = 0; n < 4; n++) {
                const int col = bn + wn + n * 16 + fr;
                const float bv = bias[col];
#pragma unroll
                for (int j = 0; j < 4; j++) {
                    const int row = bm + wm + m * 16 + fq * 4 + j;
                    float v = acc[m][n][j] + bv;
                    if (RELU) v = fmaxf(v, 0.f);
                    if (OUT_MODE == 1)
                        ((unsigned short*)C)[(size_t)row * N + col] = f2bf(v);
                    else
                        ((float*)C)[(size_t)row * N + col] = v;
                }
            }
        }
    }
}

// ========= prep: all weight cvt + gh0 gemv (fused with W_hh read) + prefill =====
__global__ __launch_bounds__(256)
void prep(const float* __restrict__ W_hh, const float* __restrict__ W_ih,
          const float* __restrict__ W1, const float* __restrict__ W2,
          const float* __restrict__ W_emb, const float* __restrict__ table,
          const float* __restrict__ state, const float* __restrict__ b_emb,
          const float* __restrict__ b_ih, const float* __restrict__ b_hh,
          unsigned short* __restrict__ W_hhb, unsigned short* __restrict__ W_ihb,
          unsigned short* __restrict__ W1b, unsigned short* __restrict__ W2b,
          unsigned short* __restrict__ W_embb, unsigned short* __restrict__ tableb,
          float* __restrict__ gh0, float* __restrict__ emb32, float* __restrict__ Gi,
          float* __restrict__ gh1, float* __restrict__ logits)
{
    int b = blockIdx.x;
    const int t = threadIdx.x;
    if (b < 3072) {   // W_hh row b: convert + fused gemv
        float4 w = *reinterpret_cast<const float4*>(W_hh + (size_t)b * H + t * 4);
        ushort4 o; o.x = f2bf(w.x); o.y = f2bf(w.y); o.z = f2bf(w.z); o.w = f2bf(w.w);
        *reinterpret_cast<ushort4*>(W_hhb + (size_t)b * H + t * 4) = o;
        float4 sv = *reinterpret_cast<const float4*>(state + t * 4);
        float s = w.x * sv.x + w.y * sv.y + w.z * sv.z + w.w * sv.w;
#pragma unroll
        for (int off = 32; off; off >>= 1) s += __shfl_down(s, off);
        __shared__ float ps[4];
        if ((t & 63) == 0) ps[t >> 6] = s;
        __syncthreads();
        if (t == 0) gh0[b] = ps[0] + ps[1] + ps[2] + ps[3] + b_hh[b];
        return;
    }
    b -= 3072;
    const float* src = nullptr; unsigned short* dst = nullptr;
    if (b < 3072)      { src = W_ih;  dst = W_ihb; }
    else if ((b -= 3072) < 1024) { src = W1; dst = W1b; }
    else if ((b -= 1024) < 1024) { src = W2; dst = W2b; }
    else if ((b -= 1024) < 1024) { src = W_emb; dst = W_embb; }
    else if ((b -= 1024) < 256)  { src = table; dst = tableb; }
    else {
        b -= 256;
        if (b < 256) {
            int i = b * 1024 + t * 4;
            *reinterpret_cast<float4*>(emb32 + i) =
                *reinterpret_cast<const float4*>(b_emb + (i & (H - 1)));
        } else if ((b -= 256) < 768) {
            int i = b * 1024 + t * 4;
            *reinterpret_cast<float4*>(Gi + i) =
                *reinterpret_cast<const float4*>(b_ih + i % H3);
        } else if ((b -= 768) < 768) {
            int i = b * 1024 + t * 4;
            *reinterpret_cast<float4*>(gh1 + i) =
                *reinterpret_cast<const float4*>(b_hh + i % H3);
        } else {
            b -= 768;
            int i = b * 1024 + t * 4;
            *reinterpret_cast<float4*>(logits + i) = (float4){0.f, 0.f, 0.f, 0.f};
        }
        return;
    }
    const int off = b * 1024 + t * 4;
    float4 v = *reinterpret_cast<const float4*>(src + off);
    ushort4 o; o.x = f2bf(v.x); o.y = f2bf(v.y); o.z = f2bf(v.z); o.w = f2bf(v.w);
    *reinterpret_cast<ushort4*>(dst + off) = o;
}

// ---------------- fp32 -> bf16 (emb) ----------------
__global__ void cvt_emb(const float* __restrict__ in, unsigned short* __restrict__ out)
{
    int i = (blockIdx.x * blockDim.x + threadIdx.x) * 4;
    float4 v = *reinterpret_cast<const float4*>(in + i);
    ushort4 o;
    o.x = f2bf(v.x); o.y = f2bf(v.y); o.z = f2bf(v.z); o.w = f2bf(v.w);
    *reinterpret_cast<ushort4*>(out + i) = o;
}

// ---------------- GRU combine kernels ----------------
__global__ void h1_combine(const float* __restrict__ Gi, const float* __restrict__ gh0,
                           const float* __restrict__ state, float* __restrict__ h1,
                           unsigned short* __restrict__ h1b)
{
    int idx = blockIdx.x * blockDim.x + threadIdx.x;
    int v = idx >> 10, h = idx & (H - 1);
    const float* g = Gi + (size_t)v * H3;
    float r = sigf(g[h] + gh0[h]);
    float z = sigf(g[H + h] + gh0[H + h]);
    float n = tanhf(fmaf(r, gh0[2 * H + h], g[2 * H + h]));
    float v2 = (1.f - z) * n + z * state[h];
    h1[idx] = v2;
    h1b[idx] = f2bf(v2);
}

__global__ void step2_both(const int* __restrict__ rel, const int* __restrict__ attr, int Nr,
                           const float* __restrict__ Gi, const float* __restrict__ gh1,
                           const float* __restrict__ h1,
                           unsigned short* __restrict__ h2b, unsigned short* __restrict__ attr_out)
{
    int idx = blockIdx.x * blockDim.x + threadIdx.x;
    int row = idx >> 10, h = idx & (H - 1);
    int t0, t1, orow = row;
    unsigned short* dst;
    if (row < Nr) { t0 = rel[row * 3 + 0]; t1 = rel[row * 3 + 1]; dst = h2b; }
    else { orow = row - Nr; t0 = attr[orow * 2 + 0]; t1 = attr[orow * 2 + 1]; dst = attr_out; }
    const float* g = Gi + (size_t)t1 * H3;
    const float* gh = gh1 + (size_t)t0 * H3;
    float r = sigf(g[h] + gh[h]);
    float z = sigf(g[H + h] + gh[H + h]);
    float n = tanhf(fmaf(r, gh[2 * H + h], g[2 * H + h]));
    float v = (1.f - z) * n + z * h1[(size_t)t0 * H + h];
    dst[(size_t)orow * H + h] = f2bf(v);
}

__global__ void step3_rel(const int* __restrict__ toks,
                          const float* __restrict__ Gi, const unsigned short* __restrict__ gh2b,
                          const unsigned short* __restrict__ h2b, unsigned short* __restrict__ outb)
{
    int idx = blockIdx.x * blockDim.x + threadIdx.x;
    int row = idx >> 10, h = idx & (H - 1);
    int t2 = toks[row * 3 + 2];
    const float* g = Gi + (size_t)t2 * H3;
    const unsigned short* gh = gh2b + (size_t)row * H3;
    float r = sigf(g[h] + bf2f(gh[h]));
    float z = sigf(g[H + h] + bf2f(gh[H + h]));
    float n = tanhf(fmaf(r, bf2f(gh[2 * H + h]), g[2 * H + h]));
    outb[idx] = f2bf((1.f - z) * n + z * bf2f(h2b[idx]));
}

// ---------------- softmax + eps smoothing ----------------
__global__ void softmax_eps(const float* __restrict__ logits, const float* __restrict__ epsp,
                            float* __restrict__ out, int N)
{
    __shared__ float smax[16], ssum[16];
    int tid = threadIdx.x;
    int nw = blockDim.x >> 6;
    float m = -INFINITY;
    for (int i = tid; i < N; i += blockDim.x) m = fmaxf(m, logits[i]);
#pragma unroll
    for (int off = 32; off; off >>= 1) m = fmaxf(m, __shfl_down(m, off));
    if ((tid & 63) == 0) smax[tid >> 6] = m;
    __syncthreads();
    float M = smax[0];
    for (int i = 1; i < nw; i++) M = fmaxf(M, smax[i]);
    float s = 0.f;
    for (int i = tid; i < N; i += blockDim.x) s += expf(logits[i] - M);
#pragma unroll
    for (int off = 32; off; off >>= 1) s += __shfl_down(s, off);
    if ((tid & 63) == 0) ssum[tid >> 6] = s;
    __syncthreads();
    float S = 0.f;
    for (int i = 0; i < nw; i++) S += ssum[i];
    float e = epsp[0];
    float mul = (1.f - e) / S;
    float add = e / (float)N;
    for (int i = tid; i < N; i += blockDim.x) out[i] = expf(logits[i] - M) * mul + add;
}

extern "C" void kernel_launch(void* const* d_in, const int* in_sizes, int n_in,
                              void* d_out, int out_size, void* d_ws, size_t ws_size,
                              hipStream_t stream)
{
    const float* state       = (const float*)d_in[0];
    const int*   rel_tokens  = (const int*)d_in[1];
    const int*   attr_tokens = (const int*)d_in[2];
    const float* table       = (const float*)d_in[3];
    const float* W_emb       = (const float*)d_in[4];
    const float* b_emb       = (const float*)d_in[5];
    const float* W_ih        = (const float*)d_in[6];
    const float* W_hh        = (const float*)d_in[7];
    const float* b_ih        = (const float*)d_in[8];
    const float* b_hh        = (const float*)d_in[9];
    const float* W1          = (const float*)d_in[10];
    const float* b1          = (const float*)d_in[11];
    const float* W2          = (const float*)d_in[12];
    const float* b2          = (const float*)d_in[13];
    const float* W3          = (const float*)d_in[14];
    const float* eps         = (const float*)d_in[16];

    const int Nr = in_sizes[1] / 3;   // 4096
    const int Na = in_sizes[2] / 2;   // 4096
    const int Ntot = Nr + Na;         // 8192

    float* ws     = (float*)d_ws;
    float* Gi     = ws;
    float* gh0    = Gi + NVOC * H3;
    float* h1     = gh0 + H3;
    float* gh1    = h1 + NVOC * H;
    float* emb32  = gh1 + NVOC * H3;
    float* logits = emb32 + NVOC * H;
    unsigned short* W_hhb   = (unsigned short*)(logits + Ntot);
    unsigned short* W_ihb   = W_hhb + (size_t)H3 * H;
    unsigned short* W1b     = W_ihb + (size_t)H3 * H;
    unsigned short* W2b     = W1b + (size_t)H * H;
    unsigned short* W_embb  = W2b + (size_t)H * H;
    unsigned short* tableb  = W_embb + (size_t)H * H;
    unsigned short* embb    = tableb + (size_t)NVOC * H;
    unsigned short* h1b     = embb + (size_t)NVOC * H;
    unsigned short* h2b     = h1b + (size_t)NVOC * H;
    unsigned short* gh2b    = h2b + (size_t)Nr * H;
    unsigned short* clauseb = gh2b + (size_t)Nr * H3;
    unsigned short* x1b     = clauseb + (size_t)Ntot * H;

    // P0: all weight cvt + gh0 gemv + bias prefills + logits zero
    prep<<<11272, 256, 0, stream>>>(W_hh, W_ih, W1, W2, W_emb, table, state,
                                    b_emb, b_ih, b_hh,
                                    W_hhb, W_ihb, W1b, W2b, W_embb, tableb,
                                    gh0, emb32, Gi, gh1, logits);

    // K1: emb32 += table @ W_emb^T  (split-K=4)                   [256,1024]
    gemm_bf16<false, 3><<<dim3((H / 128) * (NVOC / 128), 4), 256, 0, stream>>>(
        tableb, W_embb, nullptr, emb32, H, H, H / 128, H / 4, nullptr, nullptr);
    cvt_emb<<<NVOC * H / 4 / 256, 256, 0, stream>>>(emb32, embb);
    // K2: Gi += emb @ W_ih^T  (split-K=4)                         [256,3072]
    gemm_bf16<false, 3><<<dim3((H3 / 128) * (NVOC / 128), 4), 256, 0, stream>>>(
        embb, W_ihb, nullptr, Gi, H3, H, H3 / 128, H / 4, nullptr, nullptr);
    // K4: h1[v] for the 256 distinct tokens
    h1_combine<<<NVOC * H / 256, 256, 0, stream>>>(Gi, gh0, state, h1, h1b);
    // K5: gh1 += h1 @ W_hh^T  (split-K=4)                         [256,3072]
    gemm_bf16<false, 3><<<dim3((H3 / 128) * (NVOC / 128), 4), 256, 0, stream>>>(
        h1b, W_hhb, nullptr, gh1, H3, H, H3 / 128, H / 4, nullptr, nullptr);
    // K6: step 2 both branches -> h2b + clauseb[Nr:]
    step2_both<<<Ntot * (H / 256), 256, 0, stream>>>(rel_tokens, attr_tokens, Nr,
                                                     Gi, gh1, h1, h2b,
                                                     clauseb + (size_t)Nr * H);
    // K7: gh2b = h2 @ W_hh^T + b_hh     [4096,3072]  256^2 8-phase (192 blocks)
    gemm256<false, 1><<<(Nr / 256) * (H3 / 256), 512, 0, stream>>>(
        h2b, W_hhb, b_hh, gh2b, H3, H, H3 / 256, nullptr, nullptr);
    // K8: rel step 3 -> clauseb rows [0, Nr)
    step3_rel<<<Nr * (H / 256), 256, 0, stream>>>(rel_tokens, Gi, gh2b, h2b, clauseb);
    // K9: x1b = relu(clause @ W1^T + b1)   [8192,1024]  128x256 gemm_n (256 blocks)
    gemm_n<true, 1><<<(Ntot / 128) * (H / 256), 512, 0, stream>>>(
        clauseb, W1b, b1, x1b, H, H, H / 256, nullptr, nullptr);
    // K10+K11: logits += relu(x1 @ W2^T + b2) . W3   [8192]  gemm_n (256 blocks)
    gemm_n<true, 2><<<(Ntot / 128) * (H / 256), 512, 0, stream>>>(
        x1b, W2b, b2, nullptr, H, H, H / 256, W3, logits);
    // K12: softmax + eps smoothing -> d_out
    softmax_eps<<<1, 1024, 0, stream>>>(logits, eps, (float*)d_out, Ntot);
}